// Round 9
// baseline (224.946 us; speedup 1.0000x reference)
//
#include <hip/hip_runtime.h>
#include <hip/hip_bf16.h>

// Problem: AdvancedAttentionLayer  B=2, S=2048, D=1024, H=16, DH=64
// Round 20: port the attn-proven fixes into the projection GEMMs.
// r19 counters: proj_qkv 56us, MfmaUtil 16.7, VALUBusy 18.6, occ 14%,
// HBM 13%, 9.4M bank conflicts -- latency-bound 2-phase loop (2800cyc
// slot vs ~900cyc work; 155 MFMA-cyc x 3 waves / 2800 = 16.6% = measured)
// with the same structural LDS conflicts r17 killed in attn.
// gemm_tile_pipe = fragment-major LDS (conflict-free base+lane*16 reads,
// permutation in global source addrs) + counted-vmcnt double buffer
// (2 K-tiles in flight, vmcnt(8), raw barriers, never drain in-loop).
// LDS 32->64 KB (2 blocks/CU). Epilogues unchanged. attn frozen at r19
// (raw v_exp_f32 softmax, counted-vmcnt, fragment-major, split-KV).

#define B_  2
#define S_  2048
#define D_  1024
#define K_  1024
#define H_  16
#define DH_ 64
#define BS_ (B_*S_)

typedef __hip_bfloat16 bf16;
typedef __attribute__((ext_vector_type(8))) short s8v;    // 8 bf16 = 4 VGPRs
typedef __attribute__((ext_vector_type(4))) short s4v;    // 4 bf16
typedef __attribute__((ext_vector_type(4))) float f4v;    // 16x16 MFMA C/D
typedef __attribute__((ext_vector_type(16))) float f16v;  // 32x32 MFMA C/D

__device__ __forceinline__ float b2f(bf16 x) { return __bfloat162float(x); }
__device__ __forceinline__ bf16  f2b(float x) { return __float2bfloat16(x); }

__device__ __forceinline__ void gl_lds_16B(const bf16* g, bf16* l) {
    __builtin_amdgcn_global_load_lds(
        (const __attribute__((address_space(1))) unsigned int*)g,
        (__attribute__((address_space(3))) unsigned int*)l, 16, 0, 0);
}

// pack two f32 -> two bf16 in one dword (low = a)
__device__ __forceinline__ unsigned cvtpk_bf16(float a, float b) {
    unsigned r;
    asm("v_cvt_pk_bf16_f32 %0, %1, %2" : "=v"(r) : "v"(a), "v"(b));
    return r;
}
// swap hi-half lanes of a with lo-half lanes of b (lane i <-> lane i+32)
__device__ __forceinline__ void plswap(unsigned &a, unsigned &b) {
    asm("v_permlane32_swap_b32 %0, %1" : "+v"(a), "+v"(b));
}

// raw v_exp_f32 (2^x) -- compiler handles trans-op hazards
__device__ __forceinline__ float hw_exp2(float x) {
    return __builtin_amdgcn_exp2f(x);
}

// 0.125 * log2(e): folded QK^T scale so softmax uses raw exp2
#define QSCALE_ 0.1803368801f

// ---------------------------------------------------------------------------
// Fused prep kernel. Grid 5136 blocks x 256:
//   blocks [0,1024):    W transpose, z = blk>>8 (Wq/Wk/Wv/Wo), 64x64 tiles
//   blocks [1024,5120): X fp32 -> bf16, 1024 elems per block
//   blocks [5120,5136): mask int32 -> bf16 0/1
// ---------------------------------------------------------------------------
__global__ __launch_bounds__(256) void prep_kernel(
    const float* __restrict__ X, const int* __restrict__ mask,
    const float* __restrict__ Wq, const float* __restrict__ Wk,
    const float* __restrict__ Wv, const float* __restrict__ Wo,
    bf16* __restrict__ Xb, bf16* __restrict__ mkbf,
    bf16* __restrict__ WTq, bf16* __restrict__ WTk,
    bf16* __restrict__ WTv, bf16* __restrict__ WTo)
{
    __shared__ float Ls[64][68];
    const int blk = blockIdx.x;
    const int t   = threadIdx.x;

    if (blk < 1024) {
        const int z   = blk >> 8;
        const int t16 = blk & 255;
        const int k0  = (t16 >> 4) * 64;
        const int n0  = (t16 & 15) * 64;
        const float* __restrict__ W = (z == 0) ? Wq : (z == 1) ? Wk : (z == 2) ? Wv : Wo;
        bf16* __restrict__ WT       = (z == 0) ? WTq : (z == 1) ? WTk : (z == 2) ? WTv : WTo;

        const int lr = t >> 4;
        const int lc = (t & 15) * 4;
        #pragma unroll
        for (int i = 0; i < 4; i++) {
            const int k = i * 16 + lr;
            const float4 v = *(const float4*)(W + (size_t)(k0 + k) * K_ + n0 + lc);
            Ls[k][lc + 0] = v.x; Ls[k][lc + 1] = v.y;
            Ls[k][lc + 2] = v.z; Ls[k][lc + 3] = v.w;
        }
        __syncthreads();
        #pragma unroll
        for (int i = 0; i < 4; i++) {
            const int n = i * 16 + lr;
            s4v o;
            #pragma unroll
            for (int j = 0; j < 4; j++) {
                bf16 tb = f2b(Ls[lc + j][n]);
                o[j] = *(short*)&tb;
            }
            *(s4v*)(WT + (size_t)(n0 + n) * K_ + k0 + lc) = o;
        }
    } else if (blk < 5120) {
        const size_t idx = ((size_t)(blk - 1024) * 256 + t) * 4;
        const float4 v = *(const float4*)(X + idx);
        bf16 t0 = f2b(v.x), t1 = f2b(v.y), t2 = f2b(v.z), t3 = f2b(v.w);
        s4v o;
        o[0] = *(short*)&t0; o[1] = *(short*)&t1;
        o[2] = *(short*)&t2; o[3] = *(short*)&t3;
        *(s4v*)(Xb + idx) = o;
    } else {
        const int idx = (blk - 5120) * 256 + t;
        mkbf[idx] = f2b(mask[idx] ? 1.0f : 0.0f);
    }
}

// ---------------------------------------------------------------------------
// MFMA GEMM core, 128x128 tile, fragment-major LDS + counted-vmcnt pipeline.
// As/Bs each: [2 bufs][1024 slots x 16B] = 32 KB (64 KB total).
// Slot c (0..1023): fi=c>>7, ks=(c>>6)&1, row=(fi>>2)*64+(fi&3)*16+(c&15),
//                   col=ks*32+((c>>4)&3)*8  -- matches the 16x16x32 A/B frag
//                   (lane l: row l&15, k ks*32+(l>>4)*8).
// In-loop fragment reads = base + lane*16 -> conflict-free.
// vmcnt: 8 gl_lds per stage per thread; 2 tiles in flight; wait vmcnt(8)
// per iter (vmcnt(0) only on the last); raw s_barriers, no in-loop VMEM.
// ---------------------------------------------------------------------------
template <bool SWAPPED>
__device__ __forceinline__ void gemm_tile_pipe(
    const bf16* __restrict__ A, const bf16* __restrict__ BT,
    int m0, int n0, bf16* As, bf16* Bs, f4v acc[4][4])
{
    const int t    = threadIdx.x;
    const int lane = t & 63;
    const int wave = t >> 6;
    const int wr   = wave >> 1;
    const int wc   = wave & 1;

    // staging source map (per-lane constants)
    int rw[4], cl[4];
    #pragma unroll
    for (int j = 0; j < 4; j++) {
        const int c  = j * 256 + t;
        const int fi = c >> 7;
        rw[j] = (fi >> 2) * 64 + (fi & 3) * 16 + (c & 15);
        cl[j] = ((c >> 6) & 1) * 32 + ((c >> 4) & 3) * 8;
    }

    auto stage = [&](int kb, int buf) {
        #pragma unroll
        for (int j = 0; j < 4; j++) {
            const int e = (j * 256 + t) * 8;           // dest elem (16B slot)
            gl_lds_16B(A  + (size_t)(m0 + rw[j]) * K_ + kb + cl[j],
                       As + buf * 8192 + e);
            gl_lds_16B(BT + (size_t)(n0 + rw[j]) * K_ + kb + cl[j],
                       Bs + buf * 8192 + e);
        }
    };

    __builtin_amdgcn_sched_barrier(0);
    stage(0, 0);
    __builtin_amdgcn_sched_barrier(0);
    stage(64, 1);
    __builtin_amdgcn_sched_barrier(0);

    for (int it = 0; it < 16; ++it) {
        // oldest in-flight K-tile landed; NEVER drain in-loop
        if (it < 15) asm volatile("s_waitcnt vmcnt(8)" ::: "memory");
        else         asm volatile("s_waitcnt vmcnt(0)" ::: "memory");
        __builtin_amdgcn_sched_barrier(0);
        __builtin_amdgcn_s_barrier();
        __builtin_amdgcn_sched_barrier(0);

        const bf16* __restrict__ Ab = As + (it & 1) * 8192;
        const bf16* __restrict__ Bb = Bs + (it & 1) * 8192;

        __builtin_amdgcn_s_setprio(1);
        #pragma unroll
        for (int ks = 0; ks < 2; ks++) {
            s8v fA[4], fB[4];
            #pragma unroll
            for (int i = 0; i < 4; i++) {
                fA[i] = *(const s8v*)&Ab[(((wr * 4 + i) * 2 + ks) * 64 + lane) * 8];
                fB[i] = *(const s8v*)&Bb[(((wc * 4 + i) * 2 + ks) * 64 + lane) * 8];
            }
            #pragma unroll
            for (int i = 0; i < 4; i++)
                #pragma unroll
                for (int j = 0; j < 4; j++)
                    acc[i][j] = SWAPPED
                        ? __builtin_amdgcn_mfma_f32_16x16x32_bf16(fB[i], fA[j], acc[i][j], 0, 0, 0)
                        : __builtin_amdgcn_mfma_f32_16x16x32_bf16(fA[i], fB[j], acc[i][j], 0, 0, 0);
        }
        __builtin_amdgcn_s_setprio(0);

        // all waves done reading buf[it&1] before it is restaged
        __builtin_amdgcn_sched_barrier(0);
        __builtin_amdgcn_s_barrier();
        __builtin_amdgcn_sched_barrier(0);
        if (it + 2 < 16)
            stage((it + 2) * 64, it & 1);
    }
}

// ---------------------------------------------------------------------------
// QKV projection via MFMA. Grid (32, 8, 3), block 256. LDS 64 KB.
// ---------------------------------------------------------------------------
__global__ __launch_bounds__(256) void proj_qkv_kernel(
    const bf16* __restrict__ Xb,
    const bf16* __restrict__ WTq, const float* __restrict__ bq,
    const bf16* __restrict__ WTk, const float* __restrict__ bk,
    const bf16* __restrict__ WTv, const float* __restrict__ bv,
    const float* __restrict__ emo, const int* __restrict__ mask,
    bf16* __restrict__ q_ws, bf16* __restrict__ k_ws, bf16* __restrict__ v_ws)
{
    const int m0 = blockIdx.x * 128;
    const int n0 = blockIdx.y * 128;
    const int z  = blockIdx.z;

    __shared__ __align__(16) bf16 As[2 * 8192];
    __shared__ __align__(16) bf16 Bs[2 * 8192];

    const int t    = threadIdx.x;
    const int lane = t & 63;
    const int wave = t >> 6;
    const int quad = lane >> 4;
    const int l15  = lane & 15;
    const int wr   = wave >> 1;
    const int wc   = wave & 1;

    f4v acc[4][4] = {};

    if (z == 0) {
        gemm_tile_pipe<false>(Xb, WTq, m0, n0, As, Bs, acc);
        #pragma unroll
        for (int j = 0; j < 4; j++) {
            const int n  = n0 + wc * 64 + j * 16 + l15;
            const int h  = n >> 6, dh = n & 63;
            const float bias_n = bq[n] + emo[n];
            #pragma unroll
            for (int i = 0; i < 4; i++) {
                #pragma unroll
                for (int r = 0; r < 4; r++) {
                    const int m = m0 + wr * 64 + i * 16 + quad * 4 + r;
                    const int b = m >> 11, s = m & 2047;
                    q_ws[(((size_t)(b * H_ + h)) * S_ + s) * DH_ + dh] =
                        f2b((acc[i][j][r] + bias_n) * QSCALE_);
                }
            }
        }
    } else if (z == 1) {
        gemm_tile_pipe<false>(Xb, WTk, m0, n0, As, Bs, acc);
        #pragma unroll
        for (int j = 0; j < 4; j++) {
            const int n  = n0 + wc * 64 + j * 16 + l15;
            const int h  = n >> 6, dh = n & 63;
            const float bias_n = bk[n];
            #pragma unroll
            for (int i = 0; i < 4; i++) {
                #pragma unroll
                for (int r = 0; r < 4; r++) {
                    const int m = m0 + wr * 64 + i * 16 + quad * 4 + r;
                    const int b = m >> 11, s = m & 2047;
                    k_ws[(((size_t)(b * H_ + h)) * S_ + s) * DH_ + dh] =
                        f2b(acc[i][j][r] + bias_n);
                }
            }
        }
    } else {
        gemm_tile_pipe<true>(Xb, WTv, m0, n0, As, Bs, acc);
        #pragma unroll
        for (int j = 0; j < 4; j++) {
            const int m = m0 + wr * 64 + j * 16 + l15;
            const int b = m >> 11, s = m & 2047;
            const float msk = mask[b * S_ + s] ? 1.0f : 0.0f;
            #pragma unroll
            for (int i = 0; i < 4; i++) {
                #pragma unroll
                for (int r = 0; r < 4; r++) {
                    const int n  = n0 + wc * 64 + i * 16 + quad * 4 + r;
                    const int h  = n >> 6, dh = n & 63;
                    v_ws[(((size_t)(b * H_ + h)) * DH_ + dh) * S_ + s] =
                        f2b((acc[i][j][r] + bv[n]) * msk);
                }
            }
        }
    }
}

// ---------------------------------------------------------------------------
// Output projection: 128x128 tile, grid (32, 8). out = ctx @ Wo + bo (fp32).
// ---------------------------------------------------------------------------
__global__ __launch_bounds__(256) void proj_out_kernel(
    const bf16* __restrict__ ctx, const bf16* __restrict__ WTo,
    const float* __restrict__ bo, float* __restrict__ out)
{
    const int m0 = blockIdx.x * 128;
    const int n0 = blockIdx.y * 128;

    __shared__ __align__(16) bf16 As[2 * 8192];
    __shared__ __align__(16) bf16 Bs[2 * 8192];

    const int t    = threadIdx.x;
    const int lane = t & 63;
    const int wave = t >> 6;
    const int quad = lane >> 4;
    const int l15  = lane & 15;
    const int wr   = wave >> 1;
    const int wc   = wave & 1;

    f4v acc[4][4] = {};
    gemm_tile_pipe<false>(ctx, WTo, m0, n0, As, Bs, acc);

    #pragma unroll
    for (int j = 0; j < 4; j++) {
        const int n = n0 + wc * 64 + j * 16 + l15;
        const float bias_n = bo[n];
        #pragma unroll
        for (int i = 0; i < 4; i++) {
            #pragma unroll
            for (int r = 0; r < 4; r++) {
                const int m = m0 + wr * 64 + i * 16 + quad * 4 + r;
                out[(size_t)m * D_ + n] = acc[i][j][r] + bias_n;
            }
        }
    }
}

// ---------------------------------------------------------------------------
// MFMA flash attention (frozen r19): 32x32x16 MFMA, split-KV 8-wave blocks,
// fragment-major K/V LDS, counted-vmcnt pipeline, raw v_exp_f32 softmax.
// Grid (B*H=32, S/128=16), 512 threads.
// ---------------------------------------------------------------------------
__global__ __launch_bounds__(512) void attn_kernel(
    const bf16* __restrict__ q_ws, const bf16* __restrict__ k_ws,
    const bf16* __restrict__ v_ws, const bf16* __restrict__ mkbf,
    bf16* __restrict__ ctx)
{
    const int bh = blockIdx.x;
    const int q0 = blockIdx.y * 128;
    const int b  = bh >> 4;
    const int h  = bh & 15;

    // [grp][buf][kv(0=K,1=V)][4096 bf16] -- 65536 B; merge buffer overlays
    __shared__ __align__(16) bf16 lds[2][2][2][4096];
    __shared__ __align__(16) bf16 mk_lds[2][1024];   // per-group mask slice

    const int t    = threadIdx.x;
    const int wave = t >> 6;         // 0..7
    const int qsub = wave & 3;       // q subtile (32 rows)
    const int grp  = wave >> 2;      // KV half
    const int tg   = t & 255;        // thread index within group
    const int lane = t & 63;
    const int ql   = lane & 31;      // q col (QK C) / dh col (PV C)
    const int hf   = lane >> 5;

    const int kb_base = grp * 1024;  // this group's key range start

    // ---- Q as B-operand frags: col q = q0+qsub*32+ql, k = kd*16+hf*8 ----
    s8v qf[4];
    #pragma unroll
    for (int kd = 0; kd < 4; kd++)
        qf[kd] = *(const s8v*)(q_ws +
            ((size_t)bh * S_ + q0 + qsub * 32 + ql) * DH_ + kd * 16 + hf * 8);

    f16v oacc[2] = {};   // [dt]: rows=q (reg), cols=dh (ql)
    f16v osum    = {};   // denominator partial, same layout

    const bf16* __restrict__ kgbl  = k_ws + (size_t)bh * S_ * DH_;
    const bf16* __restrict__ vgbl  = v_ws + (size_t)bh * DH_ * S_;

    // staging: 2 chunks per thread per tile; chunk c = j*256 + tg
    int k_key[2], k_dh[2], v_dh[2], v_key[2];
    #pragma unroll
    for (int j = 0; j < 2; j++) {
        const int c  = j * 256 + tg;
        const int fl = c & 63;
        k_key[j] = (c >> 8) * 32 + (fl & 31);           // kt*32 + row
        k_dh[j]  = ((c >> 6) & 3) * 16 + (fl >> 5) * 8; // kd*16 + hf8
        v_dh[j]  = (c >> 8) * 32 + (fl & 31);           // dt*32 + col
        v_key[j] = ((c >> 6) & 3) * 16 + (fl >> 5) * 8; // ks*16 + hf8
    }

    auto stage = [&](int kb_abs, int buf) {
        #pragma unroll
        for (int j = 0; j < 2; j++) {
            const int e = (j * 256 + tg) * 8;          // dest elem (16B slot)
            gl_lds_16B(kgbl + (size_t)(kb_abs + k_key[j]) * DH_ + k_dh[j],
                       &lds[grp][buf][0][e]);
            gl_lds_16B(vgbl + (size_t)v_dh[j] * S_ + kb_abs + v_key[j],
                       &lds[grp][buf][1][e]);
        }
    };

    // ---- prologue: pin VMEM issue order with sched_barrier fences ----
    __builtin_amdgcn_sched_barrier(0);
    #pragma unroll
    for (int j = 0; j < 2; j++)
        gl_lds_16B(mkbf + (size_t)b * S_ + kb_base + j * 512 + lane * 8,
                   &mk_lds[grp][j * 512 + lane * 8]);
    __builtin_amdgcn_sched_barrier(0);
    stage(kb_base, 0);
    __builtin_amdgcn_sched_barrier(0);
    stage(kb_base + 64, 1);
    __builtin_amdgcn_sched_barrier(0);

    for (int it = 0; it < 16; ++it) {
        const int kb = it * 64;

        // oldest in-flight tile (and mask/qf) landed; NEVER drain in-loop
        if (it < 15) asm volatile("s_waitcnt vmcnt(4)" ::: "memory");
        else         asm volatile("s_waitcnt vmcnt(0)" ::: "memory");
        __builtin_amdgcn_sched_barrier(0);
        __builtin_amdgcn_s_barrier();      // all waves' tile-it loads landed
        __builtin_amdgcn_sched_barrier(0);

        const bf16* __restrict__ kc = &lds[grp][it & 1][0][0];
        const bf16* __restrict__ vc = &lds[grp][it & 1][1][0];

        // ---- S^T = K.Q^T: 2 key-tiles x 4 k-steps of 16 dh ----
        f16v sacc[2] = {};
        __builtin_amdgcn_s_setprio(1);
        #pragma unroll
        for (int kt = 0; kt < 2; kt++) {
            #pragma unroll
            for (int kd = 0; kd < 4; kd++) {
                const s8v kf = *(const s8v*)&kc[((kt * 4 + kd) * 64 + lane) * 8];
                sacc[kt] = __builtin_amdgcn_mfma_f32_32x32x16_bf16(kf, qf[kd], sacc[kt], 0, 0, 0);
            }
        }
        __builtin_amdgcn_s_setprio(0);

        // ---- per 16-key step: exp2 -> pack -> lane-swap -> PV + denom ----
        #pragma unroll
        for (int kt = 0; kt < 2; kt++) {
            #pragma unroll
            for (int hh = 0; hh < 2; hh++) {
                const int ks = kt * 2 + hh;     // 16-key step within 64
                float p[8];
                #pragma unroll
                for (int j = 0; j < 8; j++)
                    p[j] = hw_exp2(sacc[kt][hh * 8 + j]);
                unsigned w0 = cvtpk_bf16(p[0], p[1]);
                unsigned w1 = cvtpk_bf16(p[2], p[3]);
                unsigned w2 = cvtpk_bf16(p[4], p[5]);
                unsigned w3 = cvtpk_bf16(p[6], p[7]);
                plswap(w0, w2);
                plswap(w1, w3);
                union { unsigned u[4]; s8v v; } af;
                af.u[0] = w0; af.u[1] = w1; af.u[2] = w2; af.u[3] = w3;

                // mask fragment from LDS (same-address broadcast, no VMEM)
                const s8v mf = *(const s8v*)&mk_lds[grp][kb + ks * 16 + hf * 8];
                __builtin_amdgcn_s_setprio(1);
                osum = __builtin_amdgcn_mfma_f32_32x32x16_bf16(af.v, mf, osum, 0, 0, 0);
                #pragma unroll
                for (int dt = 0; dt < 2; dt++) {
                    const s8v vf = *(const s8v*)&vc[((dt * 4 + ks) * 64 + lane) * 8];
                    oacc[dt] = __builtin_amdgcn_mfma_f32_32x32x16_bf16(af.v, vf, oacc[dt], 0, 0, 0);
                }
                __builtin_amdgcn_s_setprio(0);
            }
        }

        // all waves done reading buf[it&1] before it is restaged
        __builtin_amdgcn_sched_barrier(0);
        __builtin_amdgcn_s_barrier();
        __builtin_amdgcn_sched_barrier(0);
        if (it + 2 < 16)
            stage(kb_base + kb + 128, it & 1);
    }

    // ---- merge the two KV-half partials through LDS (buffers now dead) ---
    float* mg = (float*)&lds[0][0][0][0];

    if (grp == 1) {
        #pragma unroll
        for (int r = 0; r < 16; r++) {
            const int qrow = (r & 3) + 8 * (r >> 2) + 4 * hf;
            #pragma unroll
            for (int dt = 0; dt < 2; dt++)
                mg[qsub * 2048 + qrow * 64 + dt * 32 + ql] = oacc[dt][r];
            if (ql == 0)
                mg[8192 + qsub * 32 + qrow] = osum[r];
        }
    }
    __syncthreads();
    if (grp == 0) {
        #pragma unroll
        for (int r = 0; r < 16; r++) {
            const int qrow = (r & 3) + 8 * (r >> 2) + 4 * hf;
            const float den = osum[r] + mg[8192 + qsub * 32 + qrow];
            const float inv = 1.0f / den;
            const int q = q0 + qsub * 32 + qrow;
            #pragma unroll
            for (int dt = 0; dt < 2; dt++) {
                const float o = oacc[dt][r] + mg[qsub * 2048 + qrow * 64 + dt * 32 + ql];
                ctx[((size_t)b * S_ + q) * D_ + h * DH_ + dt * 32 + ql] = f2b(o * inv);
            }
        }
    }
}

// ---------------------------------------------------------------------------
extern "C" void kernel_launch(void* const* d_in, const int* in_sizes, int n_in,
                              void* d_out, int out_size, void* d_ws, size_t ws_size,
                              hipStream_t stream) {
    (void)in_sizes; (void)n_in; (void)out_size; (void)ws_size;

    const float* X    = (const float*)d_in[0];
    const int*   mask = (const int*)d_in[1];
    const float* Wq   = (const float*)d_in[2];
    const float* bq   = (const float*)d_in[3];
    const float* Wk   = (const float*)d_in[4];
    const float* bk   = (const float*)d_in[5];
    const float* Wv   = (const float*)d_in[6];
    const float* bv   = (const float*)d_in[7];
    const float* emo  = (const float*)d_in[8];
    const float* Wo   = (const float*)d_in[9];
    const float* bo   = (const float*)d_in[10];
    float* out = (float*)d_out;

    bf16* q_ws = (bf16*)d_ws;                       // [B,H,S,DH]   8 MB
    bf16* k_ws = q_ws + (size_t)BS_ * D_;           // [B,H,S,DH]   8 MB
    bf16* v_ws = k_ws + (size_t)BS_ * D_;           // [B,H,DH,S]   8 MB
    bf16* ctx  = v_ws + (size_t)BS_ * D_;           // [B,S,D]      8 MB
    bf16* Xb   = ctx  + (size_t)BS_ * D_;           // [BS,D]       8 MB
    bf16* WTq  = Xb   + (size_t)BS_ * D_;           // [N,K]        2 MB
    bf16* WTk  = WTq  + (size_t)D_ * K_;
    bf16* WTv  = WTk  + (size_t)D_ * K_;
    bf16* WTo  = WTv  + (size_t)D_ * K_;
    bf16* mkbf = WTo  + (size_t)D_ * K_;            // [B*S] bf16 mask

    hipLaunchKernelGGL(prep_kernel, dim3(5136), dim3(256), 0, stream,
                       X, mask, Wq, Wk, Wv, Wo, Xb, mkbf, WTq, WTk, WTv, WTo);
    hipLaunchKernelGGL(proj_qkv_kernel, dim3(BS_ / 128, D_ / 128, 3), dim3(256), 0, stream,
                       Xb, WTq, bq, WTk, bk, WTv, bv, emo, mask, q_ws, k_ws, v_ws);
    hipLaunchKernelGGL(attn_kernel, dim3(B_ * H_, S_ / 128), dim3(512), 0, stream,
                       q_ws, k_ws, v_ws, mkbf, ctx);
    hipLaunchKernelGGL(proj_out_kernel, dim3(BS_ / 128, D_ / 128), dim3(256), 0, stream,
                       ctx, WTo, bo, out);
}

// Round 10
// 200.855 us; speedup vs baseline: 1.1199x; 1.1199x over previous
//
#include <hip/hip_runtime.h>
#include <hip/hip_bf16.h>

// Problem: AdvancedAttentionLayer  B=2, S=2048, D=1024, H=16, DH=64
// Round 21: fix r20's regression. Fragment-major LDS killed global-source
// coalescing (consecutive lanes read rows 2KB apart -> 64 scattered 16B
// transactions per wave; hbm_gbps 1048->870, MfmaUtil 16.7->14 despite
// conflicts 9.4M->0). Revert GEMM staging to the attn-r12 XOR-swizzle
// scheme which has BOTH properties: coalesced source (chunk permutation
// stays within the 128B row) AND ~conflict-free reads (2-way aliasing =
// free per m136). LDS slot (row,dchunk) holds global chunk dchunk^(row&7);
// fragment read uses chunk (ks*4+quad)^(l15&7). Counted-vmcnt double
// buffer (2 K-tiles in flight, vmcnt(8), raw barriers) kept from r20 --
// single-variable change: staging layout only. attn frozen at r19.

#define B_  2
#define S_  2048
#define D_  1024
#define K_  1024
#define H_  16
#define DH_ 64
#define BS_ (B_*S_)

typedef __hip_bfloat16 bf16;
typedef __attribute__((ext_vector_type(8))) short s8v;    // 8 bf16 = 4 VGPRs
typedef __attribute__((ext_vector_type(4))) short s4v;    // 4 bf16
typedef __attribute__((ext_vector_type(4))) float f4v;    // 16x16 MFMA C/D
typedef __attribute__((ext_vector_type(16))) float f16v;  // 32x32 MFMA C/D

__device__ __forceinline__ float b2f(bf16 x) { return __bfloat162float(x); }
__device__ __forceinline__ bf16  f2b(float x) { return __float2bfloat16(x); }

__device__ __forceinline__ void gl_lds_16B(const bf16* g, bf16* l) {
    __builtin_amdgcn_global_load_lds(
        (const __attribute__((address_space(1))) unsigned int*)g,
        (__attribute__((address_space(3))) unsigned int*)l, 16, 0, 0);
}

// pack two f32 -> two bf16 in one dword (low = a)
__device__ __forceinline__ unsigned cvtpk_bf16(float a, float b) {
    unsigned r;
    asm("v_cvt_pk_bf16_f32 %0, %1, %2" : "=v"(r) : "v"(a), "v"(b));
    return r;
}
// swap hi-half lanes of a with lo-half lanes of b (lane i <-> lane i+32)
__device__ __forceinline__ void plswap(unsigned &a, unsigned &b) {
    asm("v_permlane32_swap_b32 %0, %1" : "+v"(a), "+v"(b));
}

// raw v_exp_f32 (2^x) -- compiler handles trans-op hazards
__device__ __forceinline__ float hw_exp2(float x) {
    return __builtin_amdgcn_exp2f(x);
}

// 0.125 * log2(e): folded QK^T scale so softmax uses raw exp2
#define QSCALE_ 0.1803368801f

// ---------------------------------------------------------------------------
// Fused prep kernel. Grid 5136 blocks x 256:
//   blocks [0,1024):    W transpose, z = blk>>8 (Wq/Wk/Wv/Wo), 64x64 tiles
//   blocks [1024,5120): X fp32 -> bf16, 1024 elems per block
//   blocks [5120,5136): mask int32 -> bf16 0/1
// ---------------------------------------------------------------------------
__global__ __launch_bounds__(256) void prep_kernel(
    const float* __restrict__ X, const int* __restrict__ mask,
    const float* __restrict__ Wq, const float* __restrict__ Wk,
    const float* __restrict__ Wv, const float* __restrict__ Wo,
    bf16* __restrict__ Xb, bf16* __restrict__ mkbf,
    bf16* __restrict__ WTq, bf16* __restrict__ WTk,
    bf16* __restrict__ WTv, bf16* __restrict__ WTo)
{
    __shared__ float Ls[64][68];
    const int blk = blockIdx.x;
    const int t   = threadIdx.x;

    if (blk < 1024) {
        const int z   = blk >> 8;
        const int t16 = blk & 255;
        const int k0  = (t16 >> 4) * 64;
        const int n0  = (t16 & 15) * 64;
        const float* __restrict__ W = (z == 0) ? Wq : (z == 1) ? Wk : (z == 2) ? Wv : Wo;
        bf16* __restrict__ WT       = (z == 0) ? WTq : (z == 1) ? WTk : (z == 2) ? WTv : WTo;

        const int lr = t >> 4;
        const int lc = (t & 15) * 4;
        #pragma unroll
        for (int i = 0; i < 4; i++) {
            const int k = i * 16 + lr;
            const float4 v = *(const float4*)(W + (size_t)(k0 + k) * K_ + n0 + lc);
            Ls[k][lc + 0] = v.x; Ls[k][lc + 1] = v.y;
            Ls[k][lc + 2] = v.z; Ls[k][lc + 3] = v.w;
        }
        __syncthreads();
        #pragma unroll
        for (int i = 0; i < 4; i++) {
            const int n = i * 16 + lr;
            s4v o;
            #pragma unroll
            for (int j = 0; j < 4; j++) {
                bf16 tb = f2b(Ls[lc + j][n]);
                o[j] = *(short*)&tb;
            }
            *(s4v*)(WT + (size_t)(n0 + n) * K_ + k0 + lc) = o;
        }
    } else if (blk < 5120) {
        const size_t idx = ((size_t)(blk - 1024) * 256 + t) * 4;
        const float4 v = *(const float4*)(X + idx);
        bf16 t0 = f2b(v.x), t1 = f2b(v.y), t2 = f2b(v.z), t3 = f2b(v.w);
        s4v o;
        o[0] = *(short*)&t0; o[1] = *(short*)&t1;
        o[2] = *(short*)&t2; o[3] = *(short*)&t3;
        *(s4v*)(Xb + idx) = o;
    } else {
        const int idx = (blk - 5120) * 256 + t;
        mkbf[idx] = f2b(mask[idx] ? 1.0f : 0.0f);
    }
}

// ---------------------------------------------------------------------------
// MFMA GEMM core, 128x128 tile, XOR-swizzled LDS + counted-vmcnt pipeline.
// As/Bs each: [2 bufs][128 rows x 8 chunks x 8 bf16] = 32 KB (64 KB total).
// LDS slot (row, dchunk) holds global chunk schunk = dchunk ^ (row&7):
//   staging: slot = j*256 + t (wave-contiguous -> gl_lds dest base+lane*16),
//            row = slot>>3, source chunk = (slot&7)^(row&7)  -- within-row
//            permutation, so the 8 lanes of a row read one 128B line.
//   read:    fragment (row R, k-chunk kc=ks*4+quad) at dchunk kc^(R&7)
//            -> 2 lanes per bank-quad = free 2-way aliasing (m136).
// vmcnt: 8 gl_lds per stage per thread; 2 tiles in flight; wait vmcnt(8)
// per iter (vmcnt(0) only on the last); raw s_barriers, no in-loop VMEM.
// ---------------------------------------------------------------------------
template <bool SWAPPED>
__device__ __forceinline__ void gemm_tile_pipe(
    const bf16* __restrict__ A, const bf16* __restrict__ BT,
    int m0, int n0, bf16* As, bf16* Bs, f4v acc[4][4])
{
    const int t    = threadIdx.x;
    const int lane = t & 63;
    const int wave = t >> 6;
    const int quad = lane >> 4;
    const int l15  = lane & 15;
    const int wr   = wave >> 1;
    const int wc   = wave & 1;

    // staging source map (per-lane constants)
    int rw[4], cl[4];
    #pragma unroll
    for (int j = 0; j < 4; j++) {
        const int slot = j * 256 + t;
        rw[j] = slot >> 3;                         // tile row 0..127
        cl[j] = ((slot & 7) ^ (rw[j] & 7)) * 8;    // source chunk (swizzled)
    }

    auto stage = [&](int kb, int buf) {
        #pragma unroll
        for (int j = 0; j < 4; j++) {
            const int e = (j * 256 + t) * 8;       // linear dest elem
            gl_lds_16B(A  + (size_t)(m0 + rw[j]) * K_ + kb + cl[j],
                       As + buf * 8192 + e);
            gl_lds_16B(BT + (size_t)(n0 + rw[j]) * K_ + kb + cl[j],
                       Bs + buf * 8192 + e);
        }
    };

    __builtin_amdgcn_sched_barrier(0);
    stage(0, 0);
    __builtin_amdgcn_sched_barrier(0);
    stage(64, 1);
    __builtin_amdgcn_sched_barrier(0);

    for (int it = 0; it < 16; ++it) {
        // oldest in-flight K-tile landed; NEVER drain in-loop
        if (it < 15) asm volatile("s_waitcnt vmcnt(8)" ::: "memory");
        else         asm volatile("s_waitcnt vmcnt(0)" ::: "memory");
        __builtin_amdgcn_sched_barrier(0);
        __builtin_amdgcn_s_barrier();
        __builtin_amdgcn_sched_barrier(0);

        const bf16* __restrict__ Ab = As + (it & 1) * 8192;
        const bf16* __restrict__ Bb = Bs + (it & 1) * 8192;

        __builtin_amdgcn_s_setprio(1);
        #pragma unroll
        for (int ks = 0; ks < 2; ks++) {
            s8v fA[4], fB[4];
            #pragma unroll
            for (int i = 0; i < 4; i++) {
                const int rA = wr * 64 + i * 16 + l15;
                const int rB = wc * 64 + i * 16 + l15;
                const int cA = ((ks * 4 + quad) ^ (rA & 7)) * 8;
                const int cB = ((ks * 4 + quad) ^ (rB & 7)) * 8;
                fA[i] = *(const s8v*)&Ab[rA * 64 + cA];
                fB[i] = *(const s8v*)&Bb[rB * 64 + cB];
            }
            #pragma unroll
            for (int i = 0; i < 4; i++)
                #pragma unroll
                for (int j = 0; j < 4; j++)
                    acc[i][j] = SWAPPED
                        ? __builtin_amdgcn_mfma_f32_16x16x32_bf16(fB[i], fA[j], acc[i][j], 0, 0, 0)
                        : __builtin_amdgcn_mfma_f32_16x16x32_bf16(fA[i], fB[j], acc[i][j], 0, 0, 0);
        }
        __builtin_amdgcn_s_setprio(0);

        // all waves done reading buf[it&1] before it is restaged
        __builtin_amdgcn_sched_barrier(0);
        __builtin_amdgcn_s_barrier();
        __builtin_amdgcn_sched_barrier(0);
        if (it + 2 < 16)
            stage((it + 2) * 64, it & 1);
    }
}

// ---------------------------------------------------------------------------
// QKV projection via MFMA. Grid (32, 8, 3), block 256. LDS 64 KB.
// ---------------------------------------------------------------------------
__global__ __launch_bounds__(256) void proj_qkv_kernel(
    const bf16* __restrict__ Xb,
    const bf16* __restrict__ WTq, const float* __restrict__ bq,
    const bf16* __restrict__ WTk, const float* __restrict__ bk,
    const bf16* __restrict__ WTv, const float* __restrict__ bv,
    const float* __restrict__ emo, const int* __restrict__ mask,
    bf16* __restrict__ q_ws, bf16* __restrict__ k_ws, bf16* __restrict__ v_ws)
{
    const int m0 = blockIdx.x * 128;
    const int n0 = blockIdx.y * 128;
    const int z  = blockIdx.z;

    __shared__ __align__(16) bf16 As[2 * 8192];
    __shared__ __align__(16) bf16 Bs[2 * 8192];

    const int t    = threadIdx.x;
    const int lane = t & 63;
    const int wave = t >> 6;
    const int quad = lane >> 4;
    const int l15  = lane & 15;
    const int wr   = wave >> 1;
    const int wc   = wave & 1;

    f4v acc[4][4] = {};

    if (z == 0) {
        gemm_tile_pipe<false>(Xb, WTq, m0, n0, As, Bs, acc);
        #pragma unroll
        for (int j = 0; j < 4; j++) {
            const int n  = n0 + wc * 64 + j * 16 + l15;
            const int h  = n >> 6, dh = n & 63;
            const float bias_n = bq[n] + emo[n];
            #pragma unroll
            for (int i = 0; i < 4; i++) {
                #pragma unroll
                for (int r = 0; r < 4; r++) {
                    const int m = m0 + wr * 64 + i * 16 + quad * 4 + r;
                    const int b = m >> 11, s = m & 2047;
                    q_ws[(((size_t)(b * H_ + h)) * S_ + s) * DH_ + dh] =
                        f2b((acc[i][j][r] + bias_n) * QSCALE_);
                }
            }
        }
    } else if (z == 1) {
        gemm_tile_pipe<false>(Xb, WTk, m0, n0, As, Bs, acc);
        #pragma unroll
        for (int j = 0; j < 4; j++) {
            const int n  = n0 + wc * 64 + j * 16 + l15;
            const int h  = n >> 6, dh = n & 63;
            const float bias_n = bk[n];
            #pragma unroll
            for (int i = 0; i < 4; i++) {
                #pragma unroll
                for (int r = 0; r < 4; r++) {
                    const int m = m0 + wr * 64 + i * 16 + quad * 4 + r;
                    const int b = m >> 11, s = m & 2047;
                    k_ws[(((size_t)(b * H_ + h)) * S_ + s) * DH_ + dh] =
                        f2b(acc[i][j][r] + bias_n);
                }
            }
        }
    } else {
        gemm_tile_pipe<true>(Xb, WTv, m0, n0, As, Bs, acc);
        #pragma unroll
        for (int j = 0; j < 4; j++) {
            const int m = m0 + wr * 64 + j * 16 + l15;
            const int b = m >> 11, s = m & 2047;
            const float msk = mask[b * S_ + s] ? 1.0f : 0.0f;
            #pragma unroll
            for (int i = 0; i < 4; i++) {
                #pragma unroll
                for (int r = 0; r < 4; r++) {
                    const int n  = n0 + wc * 64 + i * 16 + quad * 4 + r;
                    const int h  = n >> 6, dh = n & 63;
                    v_ws[(((size_t)(b * H_ + h)) * DH_ + dh) * S_ + s] =
                        f2b((acc[i][j][r] + bv[n]) * msk);
                }
            }
        }
    }
}

// ---------------------------------------------------------------------------
// Output projection: 128x128 tile, grid (32, 8). out = ctx @ Wo + bo (fp32).
// ---------------------------------------------------------------------------
__global__ __launch_bounds__(256) void proj_out_kernel(
    const bf16* __restrict__ ctx, const bf16* __restrict__ WTo,
    const float* __restrict__ bo, float* __restrict__ out)
{
    const int m0 = blockIdx.x * 128;
    const int n0 = blockIdx.y * 128;

    __shared__ __align__(16) bf16 As[2 * 8192];
    __shared__ __align__(16) bf16 Bs[2 * 8192];

    const int t    = threadIdx.x;
    const int lane = t & 63;
    const int wave = t >> 6;
    const int quad = lane >> 4;
    const int l15  = lane & 15;
    const int wr   = wave >> 1;
    const int wc   = wave & 1;

    f4v acc[4][4] = {};
    gemm_tile_pipe<false>(ctx, WTo, m0, n0, As, Bs, acc);

    #pragma unroll
    for (int j = 0; j < 4; j++) {
        const int n = n0 + wc * 64 + j * 16 + l15;
        const float bias_n = bo[n];
        #pragma unroll
        for (int i = 0; i < 4; i++) {
            #pragma unroll
            for (int r = 0; r < 4; r++) {
                const int m = m0 + wr * 64 + i * 16 + quad * 4 + r;
                out[(size_t)m * D_ + n] = acc[i][j][r] + bias_n;
            }
        }
    }
}

// ---------------------------------------------------------------------------
// MFMA flash attention (frozen r19): 32x32x16 MFMA, split-KV 8-wave blocks,
// fragment-major K/V LDS, counted-vmcnt pipeline, raw v_exp_f32 softmax.
// Grid (B*H=32, S/128=16), 512 threads.
// ---------------------------------------------------------------------------
__global__ __launch_bounds__(512) void attn_kernel(
    const bf16* __restrict__ q_ws, const bf16* __restrict__ k_ws,
    const bf16* __restrict__ v_ws, const bf16* __restrict__ mkbf,
    bf16* __restrict__ ctx)
{
    const int bh = blockIdx.x;
    const int q0 = blockIdx.y * 128;
    const int b  = bh >> 4;
    const int h  = bh & 15;

    // [grp][buf][kv(0=K,1=V)][4096 bf16] -- 65536 B; merge buffer overlays
    __shared__ __align__(16) bf16 lds[2][2][2][4096];
    __shared__ __align__(16) bf16 mk_lds[2][1024];   // per-group mask slice

    const int t    = threadIdx.x;
    const int wave = t >> 6;         // 0..7
    const int qsub = wave & 3;       // q subtile (32 rows)
    const int grp  = wave >> 2;      // KV half
    const int tg   = t & 255;        // thread index within group
    const int lane = t & 63;
    const int ql   = lane & 31;      // q col (QK C) / dh col (PV C)
    const int hf   = lane >> 5;

    const int kb_base = grp * 1024;  // this group's key range start

    // ---- Q as B-operand frags: col q = q0+qsub*32+ql, k = kd*16+hf*8 ----
    s8v qf[4];
    #pragma unroll
    for (int kd = 0; kd < 4; kd++)
        qf[kd] = *(const s8v*)(q_ws +
            ((size_t)bh * S_ + q0 + qsub * 32 + ql) * DH_ + kd * 16 + hf * 8);

    f16v oacc[2] = {};   // [dt]: rows=q (reg), cols=dh (ql)
    f16v osum    = {};   // denominator partial, same layout

    const bf16* __restrict__ kgbl  = k_ws + (size_t)bh * S_ * DH_;
    const bf16* __restrict__ vgbl  = v_ws + (size_t)bh * DH_ * S_;

    // staging: 2 chunks per thread per tile; chunk c = j*256 + tg
    int k_key[2], k_dh[2], v_dh[2], v_key[2];
    #pragma unroll
    for (int j = 0; j < 2; j++) {
        const int c  = j * 256 + tg;
        const int fl = c & 63;
        k_key[j] = (c >> 8) * 32 + (fl & 31);           // kt*32 + row
        k_dh[j]  = ((c >> 6) & 3) * 16 + (fl >> 5) * 8; // kd*16 + hf8
        v_dh[j]  = (c >> 8) * 32 + (fl & 31);           // dt*32 + col
        v_key[j] = ((c >> 6) & 3) * 16 + (fl >> 5) * 8; // ks*16 + hf8
    }

    auto stage = [&](int kb_abs, int buf) {
        #pragma unroll
        for (int j = 0; j < 2; j++) {
            const int e = (j * 256 + tg) * 8;          // dest elem (16B slot)
            gl_lds_16B(kgbl + (size_t)(kb_abs + k_key[j]) * DH_ + k_dh[j],
                       &lds[grp][buf][0][e]);
            gl_lds_16B(vgbl + (size_t)v_dh[j] * S_ + kb_abs + v_key[j],
                       &lds[grp][buf][1][e]);
        }
    };

    // ---- prologue: pin VMEM issue order with sched_barrier fences ----
    __builtin_amdgcn_sched_barrier(0);
    #pragma unroll
    for (int j = 0; j < 2; j++)
        gl_lds_16B(mkbf + (size_t)b * S_ + kb_base + j * 512 + lane * 8,
                   &mk_lds[grp][j * 512 + lane * 8]);
    __builtin_amdgcn_sched_barrier(0);
    stage(kb_base, 0);
    __builtin_amdgcn_sched_barrier(0);
    stage(kb_base + 64, 1);
    __builtin_amdgcn_sched_barrier(0);

    for (int it = 0; it < 16; ++it) {
        const int kb = it * 64;

        // oldest in-flight tile (and mask/qf) landed; NEVER drain in-loop
        if (it < 15) asm volatile("s_waitcnt vmcnt(4)" ::: "memory");
        else         asm volatile("s_waitcnt vmcnt(0)" ::: "memory");
        __builtin_amdgcn_sched_barrier(0);
        __builtin_amdgcn_s_barrier();      // all waves' tile-it loads landed
        __builtin_amdgcn_sched_barrier(0);

        const bf16* __restrict__ kc = &lds[grp][it & 1][0][0];
        const bf16* __restrict__ vc = &lds[grp][it & 1][1][0];

        // ---- S^T = K.Q^T: 2 key-tiles x 4 k-steps of 16 dh ----
        f16v sacc[2] = {};
        __builtin_amdgcn_s_setprio(1);
        #pragma unroll
        for (int kt = 0; kt < 2; kt++) {
            #pragma unroll
            for (int kd = 0; kd < 4; kd++) {
                const s8v kf = *(const s8v*)&kc[((kt * 4 + kd) * 64 + lane) * 8];
                sacc[kt] = __builtin_amdgcn_mfma_f32_32x32x16_bf16(kf, qf[kd], sacc[kt], 0, 0, 0);
            }
        }
        __builtin_amdgcn_s_setprio(0);

        // ---- per 16-key step: exp2 -> pack -> lane-swap -> PV + denom ----
        #pragma unroll
        for (int kt = 0; kt < 2; kt++) {
            #pragma unroll
            for (int hh = 0; hh < 2; hh++) {
                const int ks = kt * 2 + hh;     // 16-key step within 64
                float p[8];
                #pragma unroll
                for (int j = 0; j < 8; j++)
                    p[j] = hw_exp2(sacc[kt][hh * 8 + j]);
                unsigned w0 = cvtpk_bf16(p[0], p[1]);
                unsigned w1 = cvtpk_bf16(p[2], p[3]);
                unsigned w2 = cvtpk_bf16(p[4], p[5]);
                unsigned w3 = cvtpk_bf16(p[6], p[7]);
                plswap(w0, w2);
                plswap(w1, w3);
                union { unsigned u[4]; s8v v; } af;
                af.u[0] = w0; af.u[1] = w1; af.u[2] = w2; af.u[3] = w3;

                // mask fragment from LDS (same-address broadcast, no VMEM)
                const s8v mf = *(const s8v*)&mk_lds[grp][kb + ks * 16 + hf * 8];
                __builtin_amdgcn_s_setprio(1);
                osum = __builtin_amdgcn_mfma_f32_32x32x16_bf16(af.v, mf, osum, 0, 0, 0);
                #pragma unroll
                for (int dt = 0; dt < 2; dt++) {
                    const s8v vf = *(const s8v*)&vc[((dt * 4 + ks) * 64 + lane) * 8];
                    oacc[dt] = __builtin_amdgcn_mfma_f32_32x32x16_bf16(af.v, vf, oacc[dt], 0, 0, 0);
                }
                __builtin_amdgcn_s_setprio(0);
            }
        }

        // all waves done reading buf[it&1] before it is restaged
        __builtin_amdgcn_sched_barrier(0);
        __builtin_amdgcn_s_barrier();
        __builtin_amdgcn_sched_barrier(0);
        if (it + 2 < 16)
            stage(kb_base + kb + 128, it & 1);
    }

    // ---- merge the two KV-half partials through LDS (buffers now dead) ---
    float* mg = (float*)&lds[0][0][0][0];

    if (grp == 1) {
        #pragma unroll
        for (int r = 0; r < 16; r++) {
            const int qrow = (r & 3) + 8 * (r >> 2) + 4 * hf;
            #pragma unroll
            for (int dt = 0; dt < 2; dt++)
                mg[qsub * 2048 + qrow * 64 + dt * 32 + ql] = oacc[dt][r];
            if (ql == 0)
                mg[8192 + qsub * 32 + qrow] = osum[r];
        }
    }
    __syncthreads();
    if (grp == 0) {
        #pragma unroll
        for (int r = 0; r < 16; r++) {
            const int qrow = (r & 3) + 8 * (r >> 2) + 4 * hf;
            const float den = osum[r] + mg[8192 + qsub * 32 + qrow];
            const float inv = 1.0f / den;
            const int q = q0 + qsub * 32 + qrow;
            #pragma unroll
            for (int dt = 0; dt < 2; dt++) {
                const float o = oacc[dt][r] + mg[qsub * 2048 + qrow * 64 + dt * 32 + ql];
                ctx[((size_t)b * S_ + q) * D_ + h * DH_ + dt * 32 + ql] = f2b(o * inv);
            }
        }
    }
}

// ---------------------------------------------------------------------------
extern "C" void kernel_launch(void* const* d_in, const int* in_sizes, int n_in,
                              void* d_out, int out_size, void* d_ws, size_t ws_size,
                              hipStream_t stream) {
    (void)in_sizes; (void)n_in; (void)out_size; (void)ws_size;

    const float* X    = (const float*)d_in[0];
    const int*   mask = (const int*)d_in[1];
    const float* Wq   = (const float*)d_in[2];
    const float* bq   = (const float*)d_in[3];
    const float* Wk   = (const float*)d_in[4];
    const float* bk   = (const float*)d_in[5];
    const float* Wv   = (const float*)d_in[6];
    const float* bv   = (const float*)d_in[7];
    const float* emo  = (const float*)d_in[8];
    const float* Wo   = (const float*)d_in[9];
    const float* bo   = (const float*)d_in[10];
    float* out = (float*)d_out;

    bf16* q_ws = (bf16*)d_ws;                       // [B,H,S,DH]   8 MB
    bf16* k_ws = q_ws + (size_t)BS_ * D_;           // [B,H,S,DH]   8 MB
    bf16* v_ws = k_ws + (size_t)BS_ * D_;           // [B,H,DH,S]   8 MB
    bf16* ctx  = v_ws + (size_t)BS_ * D_;           // [B,S,D]      8 MB
    bf16* Xb   = ctx  + (size_t)BS_ * D_;           // [BS,D]       8 MB
    bf16* WTq  = Xb   + (size_t)BS_ * D_;           // [N,K]        2 MB
    bf16* WTk  = WTq  + (size_t)D_ * K_;
    bf16* WTv  = WTk  + (size_t)D_ * K_;
    bf16* WTo  = WTv  + (size_t)D_ * K_;
    bf16* mkbf = WTo  + (size_t)D_ * K_;            // [B*S] bf16 mask

    hipLaunchKernelGGL(prep_kernel, dim3(5136), dim3(256), 0, stream,
                       X, mask, Wq, Wk, Wv, Wo, Xb, mkbf, WTq, WTk, WTv, WTo);
    hipLaunchKernelGGL(proj_qkv_kernel, dim3(BS_ / 128, D_ / 128, 3), dim3(256), 0, stream,
                       Xb, WTq, bq, WTk, bk, WTv, bv, emo, mask, q_ws, k_ws, v_ws);
    hipLaunchKernelGGL(attn_kernel, dim3(B_ * H_, S_ / 128), dim3(512), 0, stream,
                       q_ws, k_ws, v_ws, mkbf, ctx);
    hipLaunchKernelGGL(proj_out_kernel, dim3(BS_ / 128, D_ / 128), dim3(256), 0, stream,
                       ctx, WTo, bo, out);
}

// Round 13
// 194.892 us; speedup vs baseline: 1.1542x; 1.0306x over previous
//
#include <hip/hip_runtime.h>
#include <hip/hip_bf16.h>

// Problem: AdvancedAttentionLayer  B=2, S=2048, D=1024, H=16, DH=64
// Round 24 (= r23 resubmitted; infra failure, never measured).
// r22 failed correctness -- launch_bounds(1024,8) forced VGPR<=64
// but per-thread state needs ~80 -> scratch spills -> spill VMEM ops entered
// the vmcnt queue and corrupted the counted-vmcnt discipline (stale K/V).
// Lesson: counted-vmcnt is incompatible with spilling; 8 waves/SIMD is
// structurally out for this accumulator footprint. This round: attn /
// proj_qkv / prep reverted byte-for-byte to r21 (200.9us, passed); ONE
// contained change: proj_out moves to 64x128 tiles, grid (64,8)=512 blocks,
// LDS 48KB -> 2 blocks/CU (was 256 blocks = 1/CU, the only kernel with no
// cross-block latency hiding). Dedicated gemm_tile_pipe64 (acc[2][4],
// 6 gl_lds/stage, vmcnt(6)); same XOR-swizzle staging + counted vmcnt.

#define B_  2
#define S_  2048
#define D_  1024
#define K_  1024
#define H_  16
#define DH_ 64
#define BS_ (B_*S_)

typedef __hip_bfloat16 bf16;
typedef __attribute__((ext_vector_type(8))) short s8v;    // 8 bf16 = 4 VGPRs
typedef __attribute__((ext_vector_type(4))) short s4v;    // 4 bf16
typedef __attribute__((ext_vector_type(4))) float f4v;    // 16x16 MFMA C/D
typedef __attribute__((ext_vector_type(16))) float f16v;  // 32x32 MFMA C/D

__device__ __forceinline__ float b2f(bf16 x) { return __bfloat162float(x); }
__device__ __forceinline__ bf16  f2b(float x) { return __float2bfloat16(x); }

__device__ __forceinline__ void gl_lds_16B(const bf16* g, bf16* l) {
    __builtin_amdgcn_global_load_lds(
        (const __attribute__((address_space(1))) unsigned int*)g,
        (__attribute__((address_space(3))) unsigned int*)l, 16, 0, 0);
}

// pack two f32 -> two bf16 in one dword (low = a)
__device__ __forceinline__ unsigned cvtpk_bf16(float a, float b) {
    unsigned r;
    asm("v_cvt_pk_bf16_f32 %0, %1, %2" : "=v"(r) : "v"(a), "v"(b));
    return r;
}
// swap hi-half lanes of a with lo-half lanes of b (lane i <-> lane i+32)
__device__ __forceinline__ void plswap(unsigned &a, unsigned &b) {
    asm("v_permlane32_swap_b32 %0, %1" : "+v"(a), "+v"(b));
}

// raw v_exp_f32 (2^x) -- compiler handles trans-op hazards
__device__ __forceinline__ float hw_exp2(float x) {
    return __builtin_amdgcn_exp2f(x);
}

// 0.125 * log2(e): folded QK^T scale so softmax uses raw exp2
#define QSCALE_ 0.1803368801f

// ---------------------------------------------------------------------------
// Fused prep kernel. Grid 5136 blocks x 256 (unchanged).
// ---------------------------------------------------------------------------
__global__ __launch_bounds__(256) void prep_kernel(
    const float* __restrict__ X, const int* __restrict__ mask,
    const float* __restrict__ Wq, const float* __restrict__ Wk,
    const float* __restrict__ Wv, const float* __restrict__ Wo,
    bf16* __restrict__ Xb, bf16* __restrict__ mkbf,
    bf16* __restrict__ WTq, bf16* __restrict__ WTk,
    bf16* __restrict__ WTv, bf16* __restrict__ WTo)
{
    __shared__ float Ls[64][68];
    const int blk = blockIdx.x;
    const int t   = threadIdx.x;

    if (blk < 1024) {
        const int z   = blk >> 8;
        const int t16 = blk & 255;
        const int k0  = (t16 >> 4) * 64;
        const int n0  = (t16 & 15) * 64;
        const float* __restrict__ W = (z == 0) ? Wq : (z == 1) ? Wk : (z == 2) ? Wv : Wo;
        bf16* __restrict__ WT       = (z == 0) ? WTq : (z == 1) ? WTk : (z == 2) ? WTv : WTo;

        const int lr = t >> 4;
        const int lc = (t & 15) * 4;
        #pragma unroll
        for (int i = 0; i < 4; i++) {
            const int k = i * 16 + lr;
            const float4 v = *(const float4*)(W + (size_t)(k0 + k) * K_ + n0 + lc);
            Ls[k][lc + 0] = v.x; Ls[k][lc + 1] = v.y;
            Ls[k][lc + 2] = v.z; Ls[k][lc + 3] = v.w;
        }
        __syncthreads();
        #pragma unroll
        for (int i = 0; i < 4; i++) {
            const int n = i * 16 + lr;
            s4v o;
            #pragma unroll
            for (int j = 0; j < 4; j++) {
                bf16 tb = f2b(Ls[lc + j][n]);
                o[j] = *(short*)&tb;
            }
            *(s4v*)(WT + (size_t)(n0 + n) * K_ + k0 + lc) = o;
        }
    } else if (blk < 5120) {
        const size_t idx = ((size_t)(blk - 1024) * 256 + t) * 4;
        const float4 v = *(const float4*)(X + idx);
        bf16 t0 = f2b(v.x), t1 = f2b(v.y), t2 = f2b(v.z), t3 = f2b(v.w);
        s4v o;
        o[0] = *(short*)&t0; o[1] = *(short*)&t1;
        o[2] = *(short*)&t2; o[3] = *(short*)&t3;
        *(s4v*)(Xb + idx) = o;
    } else {
        const int idx = (blk - 5120) * 256 + t;
        mkbf[idx] = f2b(mask[idx] ? 1.0f : 0.0f);
    }
}

// ---------------------------------------------------------------------------
// MFMA GEMM core (r21): 128x128 tile, XOR-swizzled LDS + counted-vmcnt
// pipeline. Coalesced staging sources, ~conflict-free reads (2-way).
// ---------------------------------------------------------------------------
template <bool SWAPPED>
__device__ __forceinline__ void gemm_tile_pipe(
    const bf16* __restrict__ A, const bf16* __restrict__ BT,
    int m0, int n0, bf16* As, bf16* Bs, f4v acc[4][4])
{
    const int t    = threadIdx.x;
    const int lane = t & 63;
    const int wave = t >> 6;
    const int quad = lane >> 4;
    const int l15  = lane & 15;
    const int wr   = wave >> 1;
    const int wc   = wave & 1;

    int rw[4], cl[4];
    #pragma unroll
    for (int j = 0; j < 4; j++) {
        const int slot = j * 256 + t;
        rw[j] = slot >> 3;                         // tile row 0..127
        cl[j] = ((slot & 7) ^ (rw[j] & 7)) * 8;    // source chunk (swizzled)
    }

    auto stage = [&](int kb, int buf) {
        #pragma unroll
        for (int j = 0; j < 4; j++) {
            const int e = (j * 256 + t) * 8;       // linear dest elem
            gl_lds_16B(A  + (size_t)(m0 + rw[j]) * K_ + kb + cl[j],
                       As + buf * 8192 + e);
            gl_lds_16B(BT + (size_t)(n0 + rw[j]) * K_ + kb + cl[j],
                       Bs + buf * 8192 + e);
        }
    };

    __builtin_amdgcn_sched_barrier(0);
    stage(0, 0);
    __builtin_amdgcn_sched_barrier(0);
    stage(64, 1);
    __builtin_amdgcn_sched_barrier(0);

    for (int it = 0; it < 16; ++it) {
        if (it < 15) asm volatile("s_waitcnt vmcnt(8)" ::: "memory");
        else         asm volatile("s_waitcnt vmcnt(0)" ::: "memory");
        __builtin_amdgcn_sched_barrier(0);
        __builtin_amdgcn_s_barrier();
        __builtin_amdgcn_sched_barrier(0);

        const bf16* __restrict__ Ab = As + (it & 1) * 8192;
        const bf16* __restrict__ Bb = Bs + (it & 1) * 8192;

        __builtin_amdgcn_s_setprio(1);
        #pragma unroll
        for (int ks = 0; ks < 2; ks++) {
            s8v fA[4], fB[4];
            #pragma unroll
            for (int i = 0; i < 4; i++) {
                const int rA = wr * 64 + i * 16 + l15;
                const int rB = wc * 64 + i * 16 + l15;
                const int cA = ((ks * 4 + quad) ^ (rA & 7)) * 8;
                const int cB = ((ks * 4 + quad) ^ (rB & 7)) * 8;
                fA[i] = *(const s8v*)&Ab[rA * 64 + cA];
                fB[i] = *(const s8v*)&Bb[rB * 64 + cB];
            }
            #pragma unroll
            for (int i = 0; i < 4; i++)
                #pragma unroll
                for (int j = 0; j < 4; j++)
                    acc[i][j] = SWAPPED
                        ? __builtin_amdgcn_mfma_f32_16x16x32_bf16(fB[i], fA[j], acc[i][j], 0, 0, 0)
                        : __builtin_amdgcn_mfma_f32_16x16x32_bf16(fA[i], fB[j], acc[i][j], 0, 0, 0);
        }
        __builtin_amdgcn_s_setprio(0);

        __builtin_amdgcn_sched_barrier(0);
        __builtin_amdgcn_s_barrier();
        __builtin_amdgcn_sched_barrier(0);
        if (it + 2 < 16)
            stage((it + 2) * 64, it & 1);
    }
}

// ---------------------------------------------------------------------------
// MFMA GEMM core, 64x128 tile (proj_out): same XOR-swizzle + counted-vmcnt
// structure, A tile 64 rows. acc[2][4]; wave layout wr = wave>>1 (32-row
// half), wc = wave&1 (64-col half). 6 gl_lds/stage -> wait vmcnt(6).
// LDS: As 2x(64x64)=16KB, Bs 2x(128x64)=32KB.
// ---------------------------------------------------------------------------
__device__ __forceinline__ void gemm_tile_pipe64(
    const bf16* __restrict__ A, const bf16* __restrict__ BT,
    int m0, int n0, bf16* As, bf16* Bs, f4v acc[2][4])
{
    const int t    = threadIdx.x;
    const int lane = t & 63;
    const int wave = t >> 6;
    const int quad = lane >> 4;
    const int l15  = lane & 15;
    const int wr   = wave >> 1;
    const int wc   = wave & 1;

    // staging maps: A 2 chunks (rows 0..63), B 4 chunks (rows 0..127)
    int rwA[2], clA[2], rwB[4], clB[4];
    #pragma unroll
    for (int j = 0; j < 2; j++) {
        const int slot = j * 256 + t;
        rwA[j] = slot >> 3;
        clA[j] = ((slot & 7) ^ (rwA[j] & 7)) * 8;
    }
    #pragma unroll
    for (int j = 0; j < 4; j++) {
        const int slot = j * 256 + t;
        rwB[j] = slot >> 3;
        clB[j] = ((slot & 7) ^ (rwB[j] & 7)) * 8;
    }

    auto stage = [&](int kb, int buf) {
        #pragma unroll
        for (int j = 0; j < 2; j++) {
            const int e = (j * 256 + t) * 8;
            gl_lds_16B(A + (size_t)(m0 + rwA[j]) * K_ + kb + clA[j],
                       As + buf * 4096 + e);
        }
        #pragma unroll
        for (int j = 0; j < 4; j++) {
            const int e = (j * 256 + t) * 8;
            gl_lds_16B(BT + (size_t)(n0 + rwB[j]) * K_ + kb + clB[j],
                       Bs + buf * 8192 + e);
        }
    };

    __builtin_amdgcn_sched_barrier(0);
    stage(0, 0);
    __builtin_amdgcn_sched_barrier(0);
    stage(64, 1);
    __builtin_amdgcn_sched_barrier(0);

    for (int it = 0; it < 16; ++it) {
        if (it < 15) asm volatile("s_waitcnt vmcnt(6)" ::: "memory");
        else         asm volatile("s_waitcnt vmcnt(0)" ::: "memory");
        __builtin_amdgcn_sched_barrier(0);
        __builtin_amdgcn_s_barrier();
        __builtin_amdgcn_sched_barrier(0);

        const bf16* __restrict__ Ab = As + (it & 1) * 4096;
        const bf16* __restrict__ Bb = Bs + (it & 1) * 8192;

        __builtin_amdgcn_s_setprio(1);
        #pragma unroll
        for (int ks = 0; ks < 2; ks++) {
            s8v fA[2], fB[4];
            #pragma unroll
            for (int i = 0; i < 2; i++) {
                const int rA = wr * 32 + i * 16 + l15;
                const int cA = ((ks * 4 + quad) ^ (rA & 7)) * 8;
                fA[i] = *(const s8v*)&Ab[rA * 64 + cA];
            }
            #pragma unroll
            for (int i = 0; i < 4; i++) {
                const int rB = wc * 64 + i * 16 + l15;
                const int cB = ((ks * 4 + quad) ^ (rB & 7)) * 8;
                fB[i] = *(const s8v*)&Bb[rB * 64 + cB];
            }
            #pragma unroll
            for (int i = 0; i < 2; i++)
                #pragma unroll
                for (int j = 0; j < 4; j++)
                    acc[i][j] = __builtin_amdgcn_mfma_f32_16x16x32_bf16(fA[i], fB[j], acc[i][j], 0, 0, 0);
        }
        __builtin_amdgcn_s_setprio(0);

        __builtin_amdgcn_sched_barrier(0);
        __builtin_amdgcn_s_barrier();
        __builtin_amdgcn_sched_barrier(0);
        if (it + 2 < 16)
            stage((it + 2) * 64, it & 1);
    }
}

// ---------------------------------------------------------------------------
// QKV projection via MFMA. Grid (32, 8, 3), block 256. LDS 64 KB. (r21)
// ---------------------------------------------------------------------------
__global__ __launch_bounds__(256) void proj_qkv_kernel(
    const bf16* __restrict__ Xb,
    const bf16* __restrict__ WTq, const float* __restrict__ bq,
    const bf16* __restrict__ WTk, const float* __restrict__ bk,
    const bf16* __restrict__ WTv, const float* __restrict__ bv,
    const float* __restrict__ emo, const int* __restrict__ mask,
    bf16* __restrict__ q_ws, bf16* __restrict__ k_ws, bf16* __restrict__ v_ws)
{
    const int m0 = blockIdx.x * 128;
    const int n0 = blockIdx.y * 128;
    const int z  = blockIdx.z;

    __shared__ __align__(16) bf16 As[2 * 8192];
    __shared__ __align__(16) bf16 Bs[2 * 8192];

    const int t    = threadIdx.x;
    const int lane = t & 63;
    const int wave = t >> 6;
    const int quad = lane >> 4;
    const int l15  = lane & 15;
    const int wr   = wave >> 1;
    const int wc   = wave & 1;

    f4v acc[4][4] = {};

    if (z == 0) {
        gemm_tile_pipe<false>(Xb, WTq, m0, n0, As, Bs, acc);
        #pragma unroll
        for (int j = 0; j < 4; j++) {
            const int n  = n0 + wc * 64 + j * 16 + l15;
            const int h  = n >> 6, dh = n & 63;
            const float bias_n = bq[n] + emo[n];
            #pragma unroll
            for (int i = 0; i < 4; i++) {
                #pragma unroll
                for (int r = 0; r < 4; r++) {
                    const int m = m0 + wr * 64 + i * 16 + quad * 4 + r;
                    const int b = m >> 11, s = m & 2047;
                    q_ws[(((size_t)(b * H_ + h)) * S_ + s) * DH_ + dh] =
                        f2b((acc[i][j][r] + bias_n) * QSCALE_);
                }
            }
        }
    } else if (z == 1) {
        gemm_tile_pipe<false>(Xb, WTk, m0, n0, As, Bs, acc);
        #pragma unroll
        for (int j = 0; j < 4; j++) {
            const int n  = n0 + wc * 64 + j * 16 + l15;
            const int h  = n >> 6, dh = n & 63;
            const float bias_n = bk[n];
            #pragma unroll
            for (int i = 0; i < 4; i++) {
                #pragma unroll
                for (int r = 0; r < 4; r++) {
                    const int m = m0 + wr * 64 + i * 16 + quad * 4 + r;
                    const int b = m >> 11, s = m & 2047;
                    k_ws[(((size_t)(b * H_ + h)) * S_ + s) * DH_ + dh] =
                        f2b(acc[i][j][r] + bias_n);
                }
            }
        }
    } else {
        gemm_tile_pipe<true>(Xb, WTv, m0, n0, As, Bs, acc);
        #pragma unroll
        for (int j = 0; j < 4; j++) {
            const int m = m0 + wr * 64 + j * 16 + l15;
            const int b = m >> 11, s = m & 2047;
            const float msk = mask[b * S_ + s] ? 1.0f : 0.0f;
            #pragma unroll
            for (int i = 0; i < 4; i++) {
                #pragma unroll
                for (int r = 0; r < 4; r++) {
                    const int n  = n0 + wc * 64 + i * 16 + quad * 4 + r;
                    const int h  = n >> 6, dh = n & 63;
                    v_ws[(((size_t)(b * H_ + h)) * DH_ + dh) * S_ + s] =
                        f2b((acc[i][j][r] + bv[n]) * msk);
                }
            }
        }
    }
}

// ---------------------------------------------------------------------------
// Output projection: 64x128 tile, grid (64, 8) = 512 blocks (2 blocks/CU).
// out = ctx @ Wo + bo (fp32). LDS 48 KB.
// ---------------------------------------------------------------------------
__global__ __launch_bounds__(256) void proj_out_kernel(
    const bf16* __restrict__ ctx, const bf16* __restrict__ WTo,
    const float* __restrict__ bo, float* __restrict__ out)
{
    const int m0 = blockIdx.x * 64;
    const int n0 = blockIdx.y * 128;

    __shared__ __align__(16) bf16 As[2 * 4096];
    __shared__ __align__(16) bf16 Bs[2 * 8192];

    const int t    = threadIdx.x;
    const int lane = t & 63;
    const int wave = t >> 6;
    const int quad = lane >> 4;
    const int l15  = lane & 15;
    const int wr   = wave >> 1;
    const int wc   = wave & 1;

    f4v acc[2][4] = {};
    gemm_tile_pipe64(ctx, WTo, m0, n0, As, Bs, acc);

    #pragma unroll
    for (int j = 0; j < 4; j++) {
        const int n = n0 + wc * 64 + j * 16 + l15;
        const float bias_n = bo[n];
        #pragma unroll
        for (int i = 0; i < 2; i++) {
            #pragma unroll
            for (int r = 0; r < 4; r++) {
                const int m = m0 + wr * 32 + i * 16 + quad * 4 + r;
                out[(size_t)m * D_ + n] = acc[i][j][r] + bias_n;
            }
        }
    }
}

// ---------------------------------------------------------------------------
// MFMA flash attention (r21, byte-identical): 32x32x16 MFMA, split-KV
// 8-wave blocks, fragment-major K/V LDS, counted-vmcnt pipeline, raw
// v_exp_f32 softmax. Grid (B*H=32, S/128=16), 512 threads.
// ---------------------------------------------------------------------------
__global__ __launch_bounds__(512) void attn_kernel(
    const bf16* __restrict__ q_ws, const bf16* __restrict__ k_ws,
    const bf16* __restrict__ v_ws, const bf16* __restrict__ mkbf,
    bf16* __restrict__ ctx)
{
    const int bh = blockIdx.x;
    const int q0 = blockIdx.y * 128;
    const int b  = bh >> 4;
    const int h  = bh & 15;

    // [grp][buf][kv(0=K,1=V)][4096 bf16] -- 65536 B; merge buffer overlays
    __shared__ __align__(16) bf16 lds[2][2][2][4096];
    __shared__ __align__(16) bf16 mk_lds[2][1024];   // per-group mask slice

    const int t    = threadIdx.x;
    const int wave = t >> 6;         // 0..7
    const int qsub = wave & 3;       // q subtile (32 rows)
    const int grp  = wave >> 2;      // KV half
    const int tg   = t & 255;        // thread index within group
    const int lane = t & 63;
    const int ql   = lane & 31;      // q col (QK C) / dh col (PV C)
    const int hf   = lane >> 5;

    const int kb_base = grp * 1024;  // this group's key range start

    // ---- Q as B-operand frags: col q = q0+qsub*32+ql, k = kd*16+hf*8 ----
    s8v qf[4];
    #pragma unroll
    for (int kd = 0; kd < 4; kd++)
        qf[kd] = *(const s8v*)(q_ws +
            ((size_t)bh * S_ + q0 + qsub * 32 + ql) * DH_ + kd * 16 + hf * 8);

    f16v oacc[2] = {};   // [dt]: rows=q (reg), cols=dh (ql)
    f16v osum    = {};   // denominator partial, same layout

    const bf16* __restrict__ kgbl  = k_ws + (size_t)bh * S_ * DH_;
    const bf16* __restrict__ vgbl  = v_ws + (size_t)bh * DH_ * S_;

    // staging: 2 chunks per thread per tile; chunk c = j*256 + tg
    int k_key[2], k_dh[2], v_dh[2], v_key[2];
    #pragma unroll
    for (int j = 0; j < 2; j++) {
        const int c  = j * 256 + tg;
        const int fl = c & 63;
        k_key[j] = (c >> 8) * 32 + (fl & 31);           // kt*32 + row
        k_dh[j]  = ((c >> 6) & 3) * 16 + (fl >> 5) * 8; // kd*16 + hf8
        v_dh[j]  = (c >> 8) * 32 + (fl & 31);           // dt*32 + col
        v_key[j] = ((c >> 6) & 3) * 16 + (fl >> 5) * 8; // ks*16 + hf8
    }

    auto stage = [&](int kb_abs, int buf) {
        #pragma unroll
        for (int j = 0; j < 2; j++) {
            const int e = (j * 256 + tg) * 8;          // dest elem (16B slot)
            gl_lds_16B(kgbl + (size_t)(kb_abs + k_key[j]) * DH_ + k_dh[j],
                       &lds[grp][buf][0][e]);
            gl_lds_16B(vgbl + (size_t)v_dh[j] * S_ + kb_abs + v_key[j],
                       &lds[grp][buf][1][e]);
        }
    };

    // ---- prologue: pin VMEM issue order with sched_barrier fences ----
    __builtin_amdgcn_sched_barrier(0);
    #pragma unroll
    for (int j = 0; j < 2; j++)
        gl_lds_16B(mkbf + (size_t)b * S_ + kb_base + j * 512 + lane * 8,
                   &mk_lds[grp][j * 512 + lane * 8]);
    __builtin_amdgcn_sched_barrier(0);
    stage(kb_base, 0);
    __builtin_amdgcn_sched_barrier(0);
    stage(kb_base + 64, 1);
    __builtin_amdgcn_sched_barrier(0);

    for (int it = 0; it < 16; ++it) {
        const int kb = it * 64;

        // oldest in-flight tile (and mask/qf) landed; NEVER drain in-loop
        if (it < 15) asm volatile("s_waitcnt vmcnt(4)" ::: "memory");
        else         asm volatile("s_waitcnt vmcnt(0)" ::: "memory");
        __builtin_amdgcn_sched_barrier(0);
        __builtin_amdgcn_s_barrier();      // all waves' tile-it loads landed
        __builtin_amdgcn_sched_barrier(0);

        const bf16* __restrict__ kc = &lds[grp][it & 1][0][0];
        const bf16* __restrict__ vc = &lds[grp][it & 1][1][0];

        // ---- S^T = K.Q^T: 2 key-tiles x 4 k-steps of 16 dh ----
        f16v sacc[2] = {};
        __builtin_amdgcn_s_setprio(1);
        #pragma unroll
        for (int kt = 0; kt < 2; kt++) {
            #pragma unroll
            for (int kd = 0; kd < 4; kd++) {
                const s8v kf = *(const s8v*)&kc[((kt * 4 + kd) * 64 + lane) * 8];
                sacc[kt] = __builtin_amdgcn_mfma_f32_32x32x16_bf16(kf, qf[kd], sacc[kt], 0, 0, 0);
            }
        }
        __builtin_amdgcn_s_setprio(0);

        // ---- per 16-key step: exp2 -> pack -> lane-swap -> PV + denom ----
        #pragma unroll
        for (int kt = 0; kt < 2; kt++) {
            #pragma unroll
            for (int hh = 0; hh < 2; hh++) {
                const int ks = kt * 2 + hh;     // 16-key step within 64
                float p[8];
                #pragma unroll
                for (int j = 0; j < 8; j++)
                    p[j] = hw_exp2(sacc[kt][hh * 8 + j]);
                unsigned w0 = cvtpk_bf16(p[0], p[1]);
                unsigned w1 = cvtpk_bf16(p[2], p[3]);
                unsigned w2 = cvtpk_bf16(p[4], p[5]);
                unsigned w3 = cvtpk_bf16(p[6], p[7]);
                plswap(w0, w2);
                plswap(w1, w3);
                union { unsigned u[4]; s8v v; } af;
                af.u[0] = w0; af.u[1] = w1; af.u[2] = w2; af.u[3] = w3;

                // mask fragment from LDS (same-address broadcast, no VMEM)
                const s8v mf = *(const s8v*)&mk_lds[grp][kb + ks * 16 + hf * 8];
                __builtin_amdgcn_s_setprio(1);
                osum = __builtin_amdgcn_mfma_f32_32x32x16_bf16(af.v, mf, osum, 0, 0, 0);
                #pragma unroll
                for (int dt = 0; dt < 2; dt++) {
                    const s8v vf = *(const s8v*)&vc[((dt * 4 + ks) * 64 + lane) * 8];
                    oacc[dt] = __builtin_amdgcn_mfma_f32_32x32x16_bf16(af.v, vf, oacc[dt], 0, 0, 0);
                }
                __builtin_amdgcn_s_setprio(0);
            }
        }

        // all waves done reading buf[it&1] before it is restaged
        __builtin_amdgcn_sched_barrier(0);
        __builtin_amdgcn_s_barrier();
        __builtin_amdgcn_sched_barrier(0);
        if (it + 2 < 16)
            stage(kb_base + kb + 128, it & 1);
    }

    // ---- merge the two KV-half partials through LDS (buffers now dead) ---
    float* mg = (float*)&lds[0][0][0][0];

    if (grp == 1) {
        #pragma unroll
        for (int r = 0; r < 16; r++) {
            const int qrow = (r & 3) + 8 * (r >> 2) + 4 * hf;
            #pragma unroll
            for (int dt = 0; dt < 2; dt++)
                mg[qsub * 2048 + qrow * 64 + dt * 32 + ql] = oacc[dt][r];
            if (ql == 0)
                mg[8192 + qsub * 32 + qrow] = osum[r];
        }
    }
    __syncthreads();
    if (grp == 0) {
        #pragma unroll
        for (int r = 0; r < 16; r++) {
            const int qrow = (r & 3) + 8 * (r >> 2) + 4 * hf;
            const float den = osum[r] + mg[8192 + qsub * 32 + qrow];
            const float inv = 1.0f / den;
            const int q = q0 + qsub * 32 + qrow;
            #pragma unroll
            for (int dt = 0; dt < 2; dt++) {
                const float o = oacc[dt][r] + mg[qsub * 2048 + qrow * 64 + dt * 32 + ql];
                ctx[((size_t)b * S_ + q) * D_ + h * DH_ + dt * 32 + ql] = f2b(o * inv);
            }
        }
    }
}

// ---------------------------------------------------------------------------
extern "C" void kernel_launch(void* const* d_in, const int* in_sizes, int n_in,
                              void* d_out, int out_size, void* d_ws, size_t ws_size,
                              hipStream_t stream) {
    (void)in_sizes; (void)n_in; (void)out_size; (void)ws_size;

    const float* X    = (const float*)d_in[0];
    const int*   mask = (const int*)d_in[1];
    const float* Wq   = (const float*)d_in[2];
    const float* bq   = (const float*)d_in[3];
    const float* Wk   = (const float*)d_in[4];
    const float* bk   = (const float*)d_in[5];
    const float* Wv   = (const float*)d_in[6];
    const float* bv   = (const float*)d_in[7];
    const float* emo  = (const float*)d_in[8];
    const float* Wo   = (const float*)d_in[9];
    const float* bo   = (const float*)d_in[10];
    float* out = (float*)d_out;

    bf16* q_ws = (bf16*)d_ws;                       // [B,H,S,DH]   8 MB
    bf16* k_ws = q_ws + (size_t)BS_ * D_;           // [B,H,S,DH]   8 MB
    bf16* v_ws = k_ws + (size_t)BS_ * D_;           // [B,H,DH,S]   8 MB
    bf16* ctx  = v_ws + (size_t)BS_ * D_;           // [B,S,D]      8 MB
    bf16* Xb   = ctx  + (size_t)BS_ * D_;           // [BS,D]       8 MB
    bf16* WTq  = Xb   + (size_t)BS_ * D_;           // [N,K]        2 MB
    bf16* WTk  = WTq  + (size_t)D_ * K_;
    bf16* WTv  = WTk  + (size_t)D_ * K_;
    bf16* WTo  = WTv  + (size_t)D_ * K_;
    bf16* mkbf = WTo  + (size_t)D_ * K_;            // [B*S] bf16 mask

    hipLaunchKernelGGL(prep_kernel, dim3(5136), dim3(256), 0, stream,
                       X, mask, Wq, Wk, Wv, Wo, Xb, mkbf, WTq, WTk, WTv, WTo);
    hipLaunchKernelGGL(proj_qkv_kernel, dim3(BS_ / 128, D_ / 128, 3), dim3(256), 0, stream,
                       Xb, WTq, bq, WTk, bk, WTv, bv, emo, mask, q_ws, k_ws, v_ws);
    hipLaunchKernelGGL(attn_kernel, dim3(B_ * H_, S_ / 128), dim3(512), 0, stream,
                       q_ws, k_ws, v_ws, mkbf, ctx);
    hipLaunchKernelGGL(proj_out_kernel, dim3(BS_ / 64, D_ / 128), dim3(256), 0, stream,
                       ctx, WTo, bo, out);
}

// Round 14
// 190.552 us; speedup vs baseline: 1.1805x; 1.0228x over previous
//
#include <hip/hip_runtime.h>
#include <hip/hip_bf16.h>

// Problem: AdvancedAttentionLayer  B=2, S=2048, D=1024, H=16, DH=64
// Round 25: apply the r24-verified 64x128 recipe to proj_qkv. r24 passed
// at 194.9us; proj_out's 64x128/2-blocks-per-CU change gained ~6us and
// verified gemm_tile_pipe64. proj_qkv is the last low-occupancy GEMM
// (64KB LDS -> 2 blocks/CU = 2 waves/SIMD). Now: 64x128 tiles, grid
// (64,8,3)=1536 blocks, LDS 48KB -> 3 blocks/CU = 3 waves/SIMD (+50%),
// with independent blocks staggering phases across the CU. z=0/1 use
// pipe64 (acc[2][4], verified); z=2 uses new pipe64s (SWAPPED, acc[4][2],
// algebraic restriction of the proven 128-tile swapped mapping to wr*32
// row-halves). Extra B re-staging is L2-resident and pipeline-hidden.
// attn / prep / proj_out byte-identical to r24.

#define B_  2
#define S_  2048
#define D_  1024
#define K_  1024
#define H_  16
#define DH_ 64
#define BS_ (B_*S_)

typedef __hip_bfloat16 bf16;
typedef __attribute__((ext_vector_type(8))) short s8v;    // 8 bf16 = 4 VGPRs
typedef __attribute__((ext_vector_type(4))) short s4v;    // 4 bf16
typedef __attribute__((ext_vector_type(4))) float f4v;    // 16x16 MFMA C/D
typedef __attribute__((ext_vector_type(16))) float f16v;  // 32x32 MFMA C/D

__device__ __forceinline__ float b2f(bf16 x) { return __bfloat162float(x); }
__device__ __forceinline__ bf16  f2b(float x) { return __float2bfloat16(x); }

__device__ __forceinline__ void gl_lds_16B(const bf16* g, bf16* l) {
    __builtin_amdgcn_global_load_lds(
        (const __attribute__((address_space(1))) unsigned int*)g,
        (__attribute__((address_space(3))) unsigned int*)l, 16, 0, 0);
}

// pack two f32 -> two bf16 in one dword (low = a)
__device__ __forceinline__ unsigned cvtpk_bf16(float a, float b) {
    unsigned r;
    asm("v_cvt_pk_bf16_f32 %0, %1, %2" : "=v"(r) : "v"(a), "v"(b));
    return r;
}
// swap hi-half lanes of a with lo-half lanes of b (lane i <-> lane i+32)
__device__ __forceinline__ void plswap(unsigned &a, unsigned &b) {
    asm("v_permlane32_swap_b32 %0, %1" : "+v"(a), "+v"(b));
}

// raw v_exp_f32 (2^x) -- compiler handles trans-op hazards
__device__ __forceinline__ float hw_exp2(float x) {
    return __builtin_amdgcn_exp2f(x);
}

// 0.125 * log2(e): folded QK^T scale so softmax uses raw exp2
#define QSCALE_ 0.1803368801f

// ---------------------------------------------------------------------------
// Fused prep kernel. Grid 5136 blocks x 256 (unchanged).
// ---------------------------------------------------------------------------
__global__ __launch_bounds__(256) void prep_kernel(
    const float* __restrict__ X, const int* __restrict__ mask,
    const float* __restrict__ Wq, const float* __restrict__ Wk,
    const float* __restrict__ Wv, const float* __restrict__ Wo,
    bf16* __restrict__ Xb, bf16* __restrict__ mkbf,
    bf16* __restrict__ WTq, bf16* __restrict__ WTk,
    bf16* __restrict__ WTv, bf16* __restrict__ WTo)
{
    __shared__ float Ls[64][68];
    const int blk = blockIdx.x;
    const int t   = threadIdx.x;

    if (blk < 1024) {
        const int z   = blk >> 8;
        const int t16 = blk & 255;
        const int k0  = (t16 >> 4) * 64;
        const int n0  = (t16 & 15) * 64;
        const float* __restrict__ W = (z == 0) ? Wq : (z == 1) ? Wk : (z == 2) ? Wv : Wo;
        bf16* __restrict__ WT       = (z == 0) ? WTq : (z == 1) ? WTk : (z == 2) ? WTv : WTo;

        const int lr = t >> 4;
        const int lc = (t & 15) * 4;
        #pragma unroll
        for (int i = 0; i < 4; i++) {
            const int k = i * 16 + lr;
            const float4 v = *(const float4*)(W + (size_t)(k0 + k) * K_ + n0 + lc);
            Ls[k][lc + 0] = v.x; Ls[k][lc + 1] = v.y;
            Ls[k][lc + 2] = v.z; Ls[k][lc + 3] = v.w;
        }
        __syncthreads();
        #pragma unroll
        for (int i = 0; i < 4; i++) {
            const int n = i * 16 + lr;
            s4v o;
            #pragma unroll
            for (int j = 0; j < 4; j++) {
                bf16 tb = f2b(Ls[lc + j][n]);
                o[j] = *(short*)&tb;
            }
            *(s4v*)(WT + (size_t)(n0 + n) * K_ + k0 + lc) = o;
        }
    } else if (blk < 5120) {
        const size_t idx = ((size_t)(blk - 1024) * 256 + t) * 4;
        const float4 v = *(const float4*)(X + idx);
        bf16 t0 = f2b(v.x), t1 = f2b(v.y), t2 = f2b(v.z), t3 = f2b(v.w);
        s4v o;
        o[0] = *(short*)&t0; o[1] = *(short*)&t1;
        o[2] = *(short*)&t2; o[3] = *(short*)&t3;
        *(s4v*)(Xb + idx) = o;
    } else {
        const int idx = (blk - 5120) * 256 + t;
        mkbf[idx] = f2b(mask[idx] ? 1.0f : 0.0f);
    }
}

// ---------------------------------------------------------------------------
// MFMA GEMM core, 64x128 tile, non-swapped: acc[2][4] (r24-verified).
// XOR-swizzled LDS + counted-vmcnt pipeline. 6 gl_lds/stage -> vmcnt(6).
// LDS: As 2x(64x64)=16KB, Bs 2x(128x64)=32KB = 48KB.
// ---------------------------------------------------------------------------
__device__ __forceinline__ void gemm_tile_pipe64(
    const bf16* __restrict__ A, const bf16* __restrict__ BT,
    int m0, int n0, bf16* As, bf16* Bs, f4v acc[2][4])
{
    const int t    = threadIdx.x;
    const int lane = t & 63;
    const int wave = t >> 6;
    const int quad = lane >> 4;
    const int l15  = lane & 15;
    const int wr   = wave >> 1;
    const int wc   = wave & 1;

    // staging maps: A 2 chunks (rows 0..63), B 4 chunks (rows 0..127)
    int rwA[2], clA[2], rwB[4], clB[4];
    #pragma unroll
    for (int j = 0; j < 2; j++) {
        const int slot = j * 256 + t;
        rwA[j] = slot >> 3;
        clA[j] = ((slot & 7) ^ (rwA[j] & 7)) * 8;
    }
    #pragma unroll
    for (int j = 0; j < 4; j++) {
        const int slot = j * 256 + t;
        rwB[j] = slot >> 3;
        clB[j] = ((slot & 7) ^ (rwB[j] & 7)) * 8;
    }

    auto stage = [&](int kb, int buf) {
        #pragma unroll
        for (int j = 0; j < 2; j++) {
            const int e = (j * 256 + t) * 8;
            gl_lds_16B(A + (size_t)(m0 + rwA[j]) * K_ + kb + clA[j],
                       As + buf * 4096 + e);
        }
        #pragma unroll
        for (int j = 0; j < 4; j++) {
            const int e = (j * 256 + t) * 8;
            gl_lds_16B(BT + (size_t)(n0 + rwB[j]) * K_ + kb + clB[j],
                       Bs + buf * 8192 + e);
        }
    };

    __builtin_amdgcn_sched_barrier(0);
    stage(0, 0);
    __builtin_amdgcn_sched_barrier(0);
    stage(64, 1);
    __builtin_amdgcn_sched_barrier(0);

    for (int it = 0; it < 16; ++it) {
        if (it < 15) asm volatile("s_waitcnt vmcnt(6)" ::: "memory");
        else         asm volatile("s_waitcnt vmcnt(0)" ::: "memory");
        __builtin_amdgcn_sched_barrier(0);
        __builtin_amdgcn_s_barrier();
        __builtin_amdgcn_sched_barrier(0);

        const bf16* __restrict__ Ab = As + (it & 1) * 4096;
        const bf16* __restrict__ Bb = Bs + (it & 1) * 8192;

        __builtin_amdgcn_s_setprio(1);
        #pragma unroll
        for (int ks = 0; ks < 2; ks++) {
            s8v fA[2], fB[4];
            #pragma unroll
            for (int i = 0; i < 2; i++) {
                const int rA = wr * 32 + i * 16 + l15;
                const int cA = ((ks * 4 + quad) ^ (rA & 7)) * 8;
                fA[i] = *(const s8v*)&Ab[rA * 64 + cA];
            }
            #pragma unroll
            for (int i = 0; i < 4; i++) {
                const int rB = wc * 64 + i * 16 + l15;
                const int cB = ((ks * 4 + quad) ^ (rB & 7)) * 8;
                fB[i] = *(const s8v*)&Bb[rB * 64 + cB];
            }
            #pragma unroll
            for (int i = 0; i < 2; i++)
                #pragma unroll
                for (int j = 0; j < 4; j++)
                    acc[i][j] = __builtin_amdgcn_mfma_f32_16x16x32_bf16(fA[i], fB[j], acc[i][j], 0, 0, 0);
        }
        __builtin_amdgcn_s_setprio(0);

        __builtin_amdgcn_sched_barrier(0);
        __builtin_amdgcn_s_barrier();
        __builtin_amdgcn_sched_barrier(0);
        if (it + 2 < 16)
            stage((it + 2) * 64, it & 1);
    }
}

// ---------------------------------------------------------------------------
// MFMA GEMM core, 64x128 tile, SWAPPED (for the V path): acc[4][2],
// acc[i][j] = mfma(fB[i], fA[j]) -> C reg dim = n-subtile i, lane dim =
// m-subtile j. Same staging / vmcnt(6) / barriers as pipe64.
// ---------------------------------------------------------------------------
__device__ __forceinline__ void gemm_tile_pipe64s(
    const bf16* __restrict__ A, const bf16* __restrict__ BT,
    int m0, int n0, bf16* As, bf16* Bs, f4v acc[4][2])
{
    const int t    = threadIdx.x;
    const int lane = t & 63;
    const int wave = t >> 6;
    const int quad = lane >> 4;
    const int l15  = lane & 15;
    const int wr   = wave >> 1;
    const int wc   = wave & 1;

    int rwA[2], clA[2], rwB[4], clB[4];
    #pragma unroll
    for (int j = 0; j < 2; j++) {
        const int slot = j * 256 + t;
        rwA[j] = slot >> 3;
        clA[j] = ((slot & 7) ^ (rwA[j] & 7)) * 8;
    }
    #pragma unroll
    for (int j = 0; j < 4; j++) {
        const int slot = j * 256 + t;
        rwB[j] = slot >> 3;
        clB[j] = ((slot & 7) ^ (rwB[j] & 7)) * 8;
    }

    auto stage = [&](int kb, int buf) {
        #pragma unroll
        for (int j = 0; j < 2; j++) {
            const int e = (j * 256 + t) * 8;
            gl_lds_16B(A + (size_t)(m0 + rwA[j]) * K_ + kb + clA[j],
                       As + buf * 4096 + e);
        }
        #pragma unroll
        for (int j = 0; j < 4; j++) {
            const int e = (j * 256 + t) * 8;
            gl_lds_16B(BT + (size_t)(n0 + rwB[j]) * K_ + kb + clB[j],
                       Bs + buf * 8192 + e);
        }
    };

    __builtin_amdgcn_sched_barrier(0);
    stage(0, 0);
    __builtin_amdgcn_sched_barrier(0);
    stage(64, 1);
    __builtin_amdgcn_sched_barrier(0);

    for (int it = 0; it < 16; ++it) {
        if (it < 15) asm volatile("s_waitcnt vmcnt(6)" ::: "memory");
        else         asm volatile("s_waitcnt vmcnt(0)" ::: "memory");
        __builtin_amdgcn_sched_barrier(0);
        __builtin_amdgcn_s_barrier();
        __builtin_amdgcn_sched_barrier(0);

        const bf16* __restrict__ Ab = As + (it & 1) * 4096;
        const bf16* __restrict__ Bb = Bs + (it & 1) * 8192;

        __builtin_amdgcn_s_setprio(1);
        #pragma unroll
        for (int ks = 0; ks < 2; ks++) {
            s8v fA[2], fB[4];
            #pragma unroll
            for (int i = 0; i < 2; i++) {
                const int rA = wr * 32 + i * 16 + l15;
                const int cA = ((ks * 4 + quad) ^ (rA & 7)) * 8;
                fA[i] = *(const s8v*)&Ab[rA * 64 + cA];
            }
            #pragma unroll
            for (int i = 0; i < 4; i++) {
                const int rB = wc * 64 + i * 16 + l15;
                const int cB = ((ks * 4 + quad) ^ (rB & 7)) * 8;
                fB[i] = *(const s8v*)&Bb[rB * 64 + cB];
            }
            #pragma unroll
            for (int i = 0; i < 4; i++)
                #pragma unroll
                for (int j = 0; j < 2; j++)
                    acc[i][j] = __builtin_amdgcn_mfma_f32_16x16x32_bf16(fB[i], fA[j], acc[i][j], 0, 0, 0);
        }
        __builtin_amdgcn_s_setprio(0);

        __builtin_amdgcn_sched_barrier(0);
        __builtin_amdgcn_s_barrier();
        __builtin_amdgcn_sched_barrier(0);
        if (it + 2 < 16)
            stage((it + 2) * 64, it & 1);
    }
}

// ---------------------------------------------------------------------------
// QKV projection via MFMA. 64x128 tiles, grid (64, 8, 3) = 1536 blocks,
// block 256, LDS 48 KB -> 3 blocks/CU (3 waves/SIMD).
// ---------------------------------------------------------------------------
__global__ __launch_bounds__(256) void proj_qkv_kernel(
    const bf16* __restrict__ Xb,
    const bf16* __restrict__ WTq, const float* __restrict__ bq,
    const bf16* __restrict__ WTk, const float* __restrict__ bk,
    const bf16* __restrict__ WTv, const float* __restrict__ bv,
    const float* __restrict__ emo, const int* __restrict__ mask,
    bf16* __restrict__ q_ws, bf16* __restrict__ k_ws, bf16* __restrict__ v_ws)
{
    const int m0 = blockIdx.x * 64;
    const int n0 = blockIdx.y * 128;
    const int z  = blockIdx.z;

    __shared__ __align__(16) bf16 As[2 * 4096];
    __shared__ __align__(16) bf16 Bs[2 * 8192];

    const int t    = threadIdx.x;
    const int lane = t & 63;
    const int wave = t >> 6;
    const int quad = lane >> 4;
    const int l15  = lane & 15;
    const int wr   = wave >> 1;
    const int wc   = wave & 1;

    if (z == 0) {
        f4v acc[2][4] = {};
        gemm_tile_pipe64(Xb, WTq, m0, n0, As, Bs, acc);
        #pragma unroll
        for (int j = 0; j < 4; j++) {
            const int n  = n0 + wc * 64 + j * 16 + l15;
            const int h  = n >> 6, dh = n & 63;
            const float bias_n = bq[n] + emo[n];
            #pragma unroll
            for (int i = 0; i < 2; i++) {
                #pragma unroll
                for (int r = 0; r < 4; r++) {
                    const int m = m0 + wr * 32 + i * 16 + quad * 4 + r;
                    const int b = m >> 11, s = m & 2047;
                    q_ws[(((size_t)(b * H_ + h)) * S_ + s) * DH_ + dh] =
                        f2b((acc[i][j][r] + bias_n) * QSCALE_);
                }
            }
        }
    } else if (z == 1) {
        f4v acc[2][4] = {};
        gemm_tile_pipe64(Xb, WTk, m0, n0, As, Bs, acc);
        #pragma unroll
        for (int j = 0; j < 4; j++) {
            const int n  = n0 + wc * 64 + j * 16 + l15;
            const int h  = n >> 6, dh = n & 63;
            const float bias_n = bk[n];
            #pragma unroll
            for (int i = 0; i < 2; i++) {
                #pragma unroll
                for (int r = 0; r < 4; r++) {
                    const int m = m0 + wr * 32 + i * 16 + quad * 4 + r;
                    const int b = m >> 11, s = m & 2047;
                    k_ws[(((size_t)(b * H_ + h)) * S_ + s) * DH_ + dh] =
                        f2b(acc[i][j][r] + bias_n);
                }
            }
        }
    } else {
        f4v acc[4][2] = {};
        gemm_tile_pipe64s(Xb, WTv, m0, n0, As, Bs, acc);
        #pragma unroll
        for (int j = 0; j < 2; j++) {
            const int m = m0 + wr * 32 + j * 16 + l15;
            const int b = m >> 11, s = m & 2047;
            const float msk = mask[b * S_ + s] ? 1.0f : 0.0f;
            #pragma unroll
            for (int i = 0; i < 4; i++) {
                #pragma unroll
                for (int r = 0; r < 4; r++) {
                    const int n  = n0 + wc * 64 + i * 16 + quad * 4 + r;
                    const int h  = n >> 6, dh = n & 63;
                    v_ws[(((size_t)(b * H_ + h)) * DH_ + dh) * S_ + s] =
                        f2b((acc[i][j][r] + bv[n]) * msk);
                }
            }
        }
    }
}

// ---------------------------------------------------------------------------
// Output projection: 64x128 tile, grid (64, 8) = 512 blocks (r24).
// out = ctx @ Wo + bo (fp32). LDS 48 KB.
// ---------------------------------------------------------------------------
__global__ __launch_bounds__(256) void proj_out_kernel(
    const bf16* __restrict__ ctx, const bf16* __restrict__ WTo,
    const float* __restrict__ bo, float* __restrict__ out)
{
    const int m0 = blockIdx.x * 64;
    const int n0 = blockIdx.y * 128;

    __shared__ __align__(16) bf16 As[2 * 4096];
    __shared__ __align__(16) bf16 Bs[2 * 8192];

    const int t    = threadIdx.x;
    const int lane = t & 63;
    const int wave = t >> 6;
    const int quad = lane >> 4;
    const int l15  = lane & 15;
    const int wr   = wave >> 1;
    const int wc   = wave & 1;

    f4v acc[2][4] = {};
    gemm_tile_pipe64(ctx, WTo, m0, n0, As, Bs, acc);

    #pragma unroll
    for (int j = 0; j < 4; j++) {
        const int n = n0 + wc * 64 + j * 16 + l15;
        const float bias_n = bo[n];
        #pragma unroll
        for (int i = 0; i < 2; i++) {
            #pragma unroll
            for (int r = 0; r < 4; r++) {
                const int m = m0 + wr * 32 + i * 16 + quad * 4 + r;
                out[(size_t)m * D_ + n] = acc[i][j][r] + bias_n;
            }
        }
    }
}

// ---------------------------------------------------------------------------
// MFMA flash attention (r21/r24, byte-identical): 32x32x16 MFMA, split-KV
// 8-wave blocks, fragment-major K/V LDS, counted-vmcnt pipeline, raw
// v_exp_f32 softmax. Grid (B*H=32, S/128=16), 512 threads.
// ---------------------------------------------------------------------------
__global__ __launch_bounds__(512) void attn_kernel(
    const bf16* __restrict__ q_ws, const bf16* __restrict__ k_ws,
    const bf16* __restrict__ v_ws, const bf16* __restrict__ mkbf,
    bf16* __restrict__ ctx)
{
    const int bh = blockIdx.x;
    const int q0 = blockIdx.y * 128;
    const int b  = bh >> 4;
    const int h  = bh & 15;

    // [grp][buf][kv(0=K,1=V)][4096 bf16] -- 65536 B; merge buffer overlays
    __shared__ __align__(16) bf16 lds[2][2][2][4096];
    __shared__ __align__(16) bf16 mk_lds[2][1024];   // per-group mask slice

    const int t    = threadIdx.x;
    const int wave = t >> 6;         // 0..7
    const int qsub = wave & 3;       // q subtile (32 rows)
    const int grp  = wave >> 2;      // KV half
    const int tg   = t & 255;        // thread index within group
    const int lane = t & 63;
    const int ql   = lane & 31;      // q col (QK C) / dh col (PV C)
    const int hf   = lane >> 5;

    const int kb_base = grp * 1024;  // this group's key range start

    // ---- Q as B-operand frags: col q = q0+qsub*32+ql, k = kd*16+hf*8 ----
    s8v qf[4];
    #pragma unroll
    for (int kd = 0; kd < 4; kd++)
        qf[kd] = *(const s8v*)(q_ws +
            ((size_t)bh * S_ + q0 + qsub * 32 + ql) * DH_ + kd * 16 + hf * 8);

    f16v oacc[2] = {};   // [dt]: rows=q (reg), cols=dh (ql)
    f16v osum    = {};   // denominator partial, same layout

    const bf16* __restrict__ kgbl  = k_ws + (size_t)bh * S_ * DH_;
    const bf16* __restrict__ vgbl  = v_ws + (size_t)bh * DH_ * S_;

    // staging: 2 chunks per thread per tile; chunk c = j*256 + tg
    int k_key[2], k_dh[2], v_dh[2], v_key[2];
    #pragma unroll
    for (int j = 0; j < 2; j++) {
        const int c  = j * 256 + tg;
        const int fl = c & 63;
        k_key[j] = (c >> 8) * 32 + (fl & 31);           // kt*32 + row
        k_dh[j]  = ((c >> 6) & 3) * 16 + (fl >> 5) * 8; // kd*16 + hf8
        v_dh[j]  = (c >> 8) * 32 + (fl & 31);           // dt*32 + col
        v_key[j] = ((c >> 6) & 3) * 16 + (fl >> 5) * 8; // ks*16 + hf8
    }

    auto stage = [&](int kb_abs, int buf) {
        #pragma unroll
        for (int j = 0; j < 2; j++) {
            const int e = (j * 256 + tg) * 8;          // dest elem (16B slot)
            gl_lds_16B(kgbl + (size_t)(kb_abs + k_key[j]) * DH_ + k_dh[j],
                       &lds[grp][buf][0][e]);
            gl_lds_16B(vgbl + (size_t)v_dh[j] * S_ + kb_abs + v_key[j],
                       &lds[grp][buf][1][e]);
        }
    };

    // ---- prologue: pin VMEM issue order with sched_barrier fences ----
    __builtin_amdgcn_sched_barrier(0);
    #pragma unroll
    for (int j = 0; j < 2; j++)
        gl_lds_16B(mkbf + (size_t)b * S_ + kb_base + j * 512 + lane * 8,
                   &mk_lds[grp][j * 512 + lane * 8]);
    __builtin_amdgcn_sched_barrier(0);
    stage(kb_base, 0);
    __builtin_amdgcn_sched_barrier(0);
    stage(kb_base + 64, 1);
    __builtin_amdgcn_sched_barrier(0);

    for (int it = 0; it < 16; ++it) {
        const int kb = it * 64;

        // oldest in-flight tile (and mask/qf) landed; NEVER drain in-loop
        if (it < 15) asm volatile("s_waitcnt vmcnt(4)" ::: "memory");
        else         asm volatile("s_waitcnt vmcnt(0)" ::: "memory");
        __builtin_amdgcn_sched_barrier(0);
        __builtin_amdgcn_s_barrier();      // all waves' tile-it loads landed
        __builtin_amdgcn_sched_barrier(0);

        const bf16* __restrict__ kc = &lds[grp][it & 1][0][0];
        const bf16* __restrict__ vc = &lds[grp][it & 1][1][0];

        // ---- S^T = K.Q^T: 2 key-tiles x 4 k-steps of 16 dh ----
        f16v sacc[2] = {};
        __builtin_amdgcn_s_setprio(1);
        #pragma unroll
        for (int kt = 0; kt < 2; kt++) {
            #pragma unroll
            for (int kd = 0; kd < 4; kd++) {
                const s8v kf = *(const s8v*)&kc[((kt * 4 + kd) * 64 + lane) * 8];
                sacc[kt] = __builtin_amdgcn_mfma_f32_32x32x16_bf16(kf, qf[kd], sacc[kt], 0, 0, 0);
            }
        }
        __builtin_amdgcn_s_setprio(0);

        // ---- per 16-key step: exp2 -> pack -> lane-swap -> PV + denom ----
        #pragma unroll
        for (int kt = 0; kt < 2; kt++) {
            #pragma unroll
            for (int hh = 0; hh < 2; hh++) {
                const int ks = kt * 2 + hh;     // 16-key step within 64
                float p[8];
                #pragma unroll
                for (int j = 0; j < 8; j++)
                    p[j] = hw_exp2(sacc[kt][hh * 8 + j]);
                unsigned w0 = cvtpk_bf16(p[0], p[1]);
                unsigned w1 = cvtpk_bf16(p[2], p[3]);
                unsigned w2 = cvtpk_bf16(p[4], p[5]);
                unsigned w3 = cvtpk_bf16(p[6], p[7]);
                plswap(w0, w2);
                plswap(w1, w3);
                union { unsigned u[4]; s8v v; } af;
                af.u[0] = w0; af.u[1] = w1; af.u[2] = w2; af.u[3] = w3;

                // mask fragment from LDS (same-address broadcast, no VMEM)
                const s8v mf = *(const s8v*)&mk_lds[grp][kb + ks * 16 + hf * 8];
                __builtin_amdgcn_s_setprio(1);
                osum = __builtin_amdgcn_mfma_f32_32x32x16_bf16(af.v, mf, osum, 0, 0, 0);
                #pragma unroll
                for (int dt = 0; dt < 2; dt++) {
                    const s8v vf = *(const s8v*)&vc[((dt * 4 + ks) * 64 + lane) * 8];
                    oacc[dt] = __builtin_amdgcn_mfma_f32_32x32x16_bf16(af.v, vf, oacc[dt], 0, 0, 0);
                }
                __builtin_amdgcn_s_setprio(0);
            }
        }

        // all waves done reading buf[it&1] before it is restaged
        __builtin_amdgcn_sched_barrier(0);
        __builtin_amdgcn_s_barrier();
        __builtin_amdgcn_sched_barrier(0);
        if (it + 2 < 16)
            stage(kb_base + kb + 128, it & 1);
    }

    // ---- merge the two KV-half partials through LDS (buffers now dead) ---
    float* mg = (float*)&lds[0][0][0][0];

    if (grp == 1) {
        #pragma unroll
        for (int r = 0; r < 16; r++) {
            const int qrow = (r & 3) + 8 * (r >> 2) + 4 * hf;
            #pragma unroll
            for (int dt = 0; dt < 2; dt++)
                mg[qsub * 2048 + qrow * 64 + dt * 32 + ql] = oacc[dt][r];
            if (ql == 0)
                mg[8192 + qsub * 32 + qrow] = osum[r];
        }
    }
    __syncthreads();
    if (grp == 0) {
        #pragma unroll
        for (int r = 0; r < 16; r++) {
            const int qrow = (r & 3) + 8 * (r >> 2) + 4 * hf;
            const float den = osum[r] + mg[8192 + qsub * 32 + qrow];
            const float inv = 1.0f / den;
            const int q = q0 + qsub * 32 + qrow;
            #pragma unroll
            for (int dt = 0; dt < 2; dt++) {
                const float o = oacc[dt][r] + mg[qsub * 2048 + qrow * 64 + dt * 32 + ql];
                ctx[((size_t)b * S_ + q) * D_ + h * DH_ + dt * 32 + ql] = f2b(o * inv);
            }
        }
    }
}

// ---------------------------------------------------------------------------
extern "C" void kernel_launch(void* const* d_in, const int* in_sizes, int n_in,
                              void* d_out, int out_size, void* d_ws, size_t ws_size,
                              hipStream_t stream) {
    (void)in_sizes; (void)n_in; (void)out_size; (void)ws_size;

    const float* X    = (const float*)d_in[0];
    const int*   mask = (const int*)d_in[1];
    const float* Wq   = (const float*)d_in[2];
    const float* bq   = (const float*)d_in[3];
    const float* Wk   = (const float*)d_in[4];
    const float* bk   = (const float*)d_in[5];
    const float* Wv   = (const float*)d_in[6];
    const float* bv   = (const float*)d_in[7];
    const float* emo  = (const float*)d_in[8];
    const float* Wo   = (const float*)d_in[9];
    const float* bo   = (const float*)d_in[10];
    float* out = (float*)d_out;

    bf16* q_ws = (bf16*)d_ws;                       // [B,H,S,DH]   8 MB
    bf16* k_ws = q_ws + (size_t)BS_ * D_;           // [B,H,S,DH]   8 MB
    bf16* v_ws = k_ws + (size_t)BS_ * D_;           // [B,H,DH,S]   8 MB
    bf16* ctx  = v_ws + (size_t)BS_ * D_;           // [B,S,D]      8 MB
    bf16* Xb   = ctx  + (size_t)BS_ * D_;           // [BS,D]       8 MB
    bf16* WTq  = Xb   + (size_t)BS_ * D_;           // [N,K]        2 MB
    bf16* WTk  = WTq  + (size_t)D_ * K_;
    bf16* WTv  = WTk  + (size_t)D_ * K_;
    bf16* WTo  = WTv  + (size_t)D_ * K_;
    bf16* mkbf = WTo  + (size_t)D_ * K_;            // [B*S] bf16 mask

    hipLaunchKernelGGL(prep_kernel, dim3(5136), dim3(256), 0, stream,
                       X, mask, Wq, Wk, Wv, Wo, Xb, mkbf, WTq, WTk, WTv, WTo);
    hipLaunchKernelGGL(proj_qkv_kernel, dim3(BS_ / 64, D_ / 128, 3), dim3(256), 0, stream,
                       Xb, WTq, bq, WTk, bk, WTv, bv, emo, mask, q_ws, k_ws, v_ws);
    hipLaunchKernelGGL(attn_kernel, dim3(B_ * H_, S_ / 128), dim3(512), 0, stream,
                       q_ws, k_ws, v_ws, mkbf, ctx);
    hipLaunchKernelGGL(proj_out_kernel, dim3(BS_ / 64, D_ / 128), dim3(256), 0, stream,
                       ctx, WTo, bo, out);
}